// Round 1
// baseline (532.222 us; speedup 1.0000x reference)
//
#include <hip/hip_runtime.h>
#include <stdint.h>

typedef unsigned short u16;
typedef __bf16 bf16x8 __attribute__((ext_vector_type(8)));
typedef float f32x4 __attribute__((ext_vector_type(4)));

#define TTOK 2048
#define DIMSZ 1024
#define NEXP 18         // 16 routed + 2 pseudo (shared expert split in two 512 chunks)
#define INTERSZ 512
#define KCAT (NEXP * INTERSZ)   // 9216

__device__ __forceinline__ u16 f2bf(float f) {
    unsigned int u = __builtin_bit_cast(unsigned int, f);
    unsigned int r = u + 0x7FFFu + ((u >> 16) & 1u);
    return (u16)(r >> 16);
}

__device__ __forceinline__ void gl2lds16(const void* g, void* l) {
    __builtin_amdgcn_global_load_lds(
        (const __attribute__((address_space(1))) void*)(uintptr_t)g,
        (__attribute__((address_space(3))) void*)(uintptr_t)l,
        16, 0, 0);
}

// ---- cast w1|sw1 (or w3|sw3) fp32 -> bf16, concatenated [18][512][1024] ----
__global__ void cast_w13(const float* __restrict__ w, const float* __restrict__ sw,
                         u16* __restrict__ dst) {
    const int n4 = NEXP * INTERSZ * DIMSZ / 4;       // 2,359,296
    const int routed4 = 16 * INTERSZ * DIMSZ / 4;    // 2,097,152
    for (int i = blockIdx.x * blockDim.x + threadIdx.x; i < n4;
         i += gridDim.x * blockDim.x) {
        float4 v = (i < routed4) ? ((const float4*)w)[i]
                                 : ((const float4*)sw)[i - routed4];
        ushort4 o;
        o.x = f2bf(v.x); o.y = f2bf(v.y); o.z = f2bf(v.z); o.w = f2bf(v.w);
        *(ushort4*)&dst[(size_t)i * 4] = o;
    }
}

// ---- build W2cat bf16 [1024][9216]: W2cat[d][e*512+i] = w2[e][d][i], tail = sw2[d][:] ----
__global__ void cast_w2cat(const float* __restrict__ w2, const float* __restrict__ sw2,
                           u16* __restrict__ dst) {
    const int n4 = DIMSZ * KCAT / 4;
    for (int i = blockIdx.x * blockDim.x + threadIdx.x; i < n4;
         i += gridDim.x * blockDim.x) {
        int flat = i * 4;
        int d = flat / KCAT;
        int k = flat - d * KCAT;
        const float* src;
        if (k < 16 * INTERSZ) {
            int e = k >> 9;
            int ii = k & 511;
            src = w2 + ((size_t)e * DIMSZ + d) * INTERSZ + ii;
        } else {
            src = sw2 + (size_t)d * 1024 + (k - 16 * INTERSZ);
        }
        float4 v = *(const float4*)src;
        ushort4 o;
        o.x = f2bf(v.x); o.y = f2bf(v.y); o.z = f2bf(v.z); o.w = f2bf(v.w);
        *(ushort4*)&dst[(size_t)i * 4] = o;
    }
}

// ---- gate: fp32 scores, sigmoid, top-2, normalized weights; also cast x -> bf16 ----
__global__ __launch_bounds__(256) void gate_kernel(
    const float* __restrict__ x, const float* __restrict__ gw,
    float* __restrict__ gate, u16* __restrict__ Xbf) {
    int wave = threadIdx.x >> 6, lane = threadIdx.x & 63;
    int t = blockIdx.x * 4 + wave;
    const float* xr = x + (size_t)t * DIMSZ;
    float xv[16];
    #pragma unroll
    for (int j = 0; j < 16; ++j) xv[j] = xr[lane + 64 * j];
    float acc[16];
    #pragma unroll
    for (int e = 0; e < 16; ++e) {
        const float* g = gw + e * DIMSZ;
        float a = 0.f;
        #pragma unroll
        for (int j = 0; j < 16; ++j) a += xv[j] * g[lane + 64 * j];
        acc[e] = a;
    }
    #pragma unroll
    for (int off = 32; off > 0; off >>= 1) {
        #pragma unroll
        for (int e = 0; e < 16; ++e) acc[e] += __shfl_xor(acc[e], off);
    }
    float s[16];
    #pragma unroll
    for (int e = 0; e < 16; ++e) s[e] = 1.f / (1.f + expf(-acc[e]));
    // top-2, first-index wins ties (strict >) to match jax top_k
    int i0 = 0; float v0 = s[0];
    #pragma unroll
    for (int e = 1; e < 16; ++e) { if (s[e] > v0) { v0 = s[e]; i0 = e; } }
    int i1 = -1; float v1 = -1e30f;
    #pragma unroll
    for (int e = 0; e < 16; ++e) { if (e != i0 && s[e] > v1) { v1 = s[e]; i1 = e; } }
    float inv = 1.f / (v0 + v1);
    if (lane < 16)
        gate[t * 16 + lane] = (lane == i0) ? v0 * inv : ((lane == i1) ? v1 * inv : 0.f);
    #pragma unroll
    for (int j = 0; j < 16; ++j)
        Xbf[(size_t)t * DIMSZ + lane + 64 * j] = f2bf(xv[j]);
}

// ---- GEMM1: H[t, e*512+n] = gate[t,e] * silu(X·w1[e]^T) * (X·w3[e]^T) ----
// BM=128 BN=128 BK=64, 4 waves (2x2), wave tile 64x64, dual accumulators.
__global__ __launch_bounds__(256) void gemm1(
    const u16* __restrict__ Xbf, const u16* __restrict__ W1b,
    const u16* __restrict__ W3b, const float* __restrict__ gate,
    u16* __restrict__ H) {
    __shared__ u16 As[128 * 64], B1s[128 * 64], B3s[128 * 64];
    const int e = blockIdx.z;
    const int m0 = blockIdx.y * 128, n0 = blockIdx.x * 128;
    const u16* A0 = Xbf + (size_t)m0 * DIMSZ;
    const size_t eoff = (size_t)e * INTERSZ * DIMSZ;
    const u16* B1 = W1b + eoff + (size_t)n0 * DIMSZ;
    const u16* B3 = W3b + eoff + (size_t)n0 * DIMSZ;
    const int tid = threadIdx.x;

    int rowi[4], cgsi[4];
    #pragma unroll
    for (int i = 0; i < 4; ++i) {
        int c = tid + i * 256;
        rowi[i] = c >> 3;
        cgsi[i] = ((c & 7) ^ (rowi[i] & 7)) * 8;   // XOR-swizzled source col-group (elements)
    }
    f32x4 acc1[4][4] = {}; f32x4 acc3[4][4] = {};
    const int wave = tid >> 6, lane = tid & 63;
    const int wm = (wave >> 1) * 64, wn = (wave & 1) * 64;
    const int lr = lane & 15, lq = lane >> 4;

    for (int kt = 0; kt < DIMSZ / 64; ++kt) {
        const int k0 = kt * 64;
        #pragma unroll
        for (int i = 0; i < 4; ++i) {
            int c = tid + i * 256;
            int off = rowi[i] * DIMSZ + k0 + cgsi[i];
            gl2lds16(A0 + off, &As[c * 8]);
            gl2lds16(B1 + off, &B1s[c * 8]);
            gl2lds16(B3 + off, &B3s[c * 8]);
        }
        __syncthreads();
        #pragma unroll
        for (int ks = 0; ks < 2; ++ks) {
            bf16x8 af[4], b1f[4], b3f[4];
            const int g = lq + ks * 4;
            #pragma unroll
            for (int mt = 0; mt < 4; ++mt) {
                int m = wm + mt * 16 + lr;
                af[mt] = *(const bf16x8*)&As[(m * 8 + (g ^ (m & 7))) * 8];
            }
            #pragma unroll
            for (int nt = 0; nt < 4; ++nt) {
                int n = wn + nt * 16 + lr;
                int ch = (n * 8 + (g ^ (n & 7))) * 8;
                b1f[nt] = *(const bf16x8*)&B1s[ch];
                b3f[nt] = *(const bf16x8*)&B3s[ch];
            }
            #pragma unroll
            for (int mt = 0; mt < 4; ++mt) {
                #pragma unroll
                for (int nt = 0; nt < 4; ++nt) {
                    acc1[mt][nt] = __builtin_amdgcn_mfma_f32_16x16x32_bf16(af[mt], b1f[nt], acc1[mt][nt], 0, 0, 0);
                    acc3[mt][nt] = __builtin_amdgcn_mfma_f32_16x16x32_bf16(af[mt], b3f[nt], acc3[mt][nt], 0, 0, 0);
                }
            }
        }
        __syncthreads();
    }
    // epilogue: silu(h1)*h3*gate -> bf16
    #pragma unroll
    for (int mt = 0; mt < 4; ++mt) {
        #pragma unroll
        for (int nt = 0; nt < 4; ++nt) {
            #pragma unroll
            for (int r = 0; r < 4; ++r) {
                int m = wm + mt * 16 + lq * 4 + r;
                int n = wn + nt * 16 + lr;
                int t = m0 + m;
                float gwv = (e < 16) ? gate[t * 16 + e] : 1.0f;
                float h1 = acc1[mt][nt][r], h3 = acc3[mt][nt][r];
                float hv = h1 / (1.f + __expf(-h1)) * h3 * gwv;
                H[(size_t)t * KCAT + e * INTERSZ + n0 + n] = f2bf(hv);
            }
        }
    }
}

// ---- GEMM2: out[t,d] = sum_k H[t,k] * W2cat[d,k]; BM=128 BN=64 BK=64 ----
__global__ __launch_bounds__(256) void gemm2(
    const u16* __restrict__ H, const u16* __restrict__ W2cat,
    float* __restrict__ out) {
    __shared__ u16 As[128 * 64], Bs[64 * 64];
    const int m0 = blockIdx.y * 128, n0 = blockIdx.x * 64;
    const u16* A0 = H + (size_t)m0 * KCAT;
    const u16* B0 = W2cat + (size_t)n0 * KCAT;
    const int tid = threadIdx.x;
    const int wave = tid >> 6, lane = tid & 63;
    const int wm = (wave >> 1) * 64, wn = (wave & 1) * 32;
    const int lr = lane & 15, lq = lane >> 4;

    f32x4 acc[4][2] = {};
    for (int kt = 0; kt < KCAT / 64; ++kt) {
        const int k0 = kt * 64;
        #pragma unroll
        for (int i = 0; i < 4; ++i) {
            int c = tid + i * 256;
            int row = c >> 3;
            int cgs = ((c & 7) ^ (row & 7)) * 8;
            gl2lds16(A0 + (size_t)row * KCAT + k0 + cgs, &As[c * 8]);
        }
        #pragma unroll
        for (int i = 0; i < 2; ++i) {
            int c = tid + i * 256;
            int row = c >> 3;
            int cgs = ((c & 7) ^ (row & 7)) * 8;
            gl2lds16(B0 + (size_t)row * KCAT + k0 + cgs, &Bs[c * 8]);
        }
        __syncthreads();
        #pragma unroll
        for (int ks = 0; ks < 2; ++ks) {
            bf16x8 af[4], bf[2];
            const int g = lq + ks * 4;
            #pragma unroll
            for (int mt = 0; mt < 4; ++mt) {
                int m = wm + mt * 16 + lr;
                af[mt] = *(const bf16x8*)&As[(m * 8 + (g ^ (m & 7))) * 8];
            }
            #pragma unroll
            for (int nt = 0; nt < 2; ++nt) {
                int n = wn + nt * 16 + lr;
                bf[nt] = *(const bf16x8*)&Bs[(n * 8 + (g ^ (n & 7))) * 8];
            }
            #pragma unroll
            for (int mt = 0; mt < 4; ++mt) {
                #pragma unroll
                for (int nt = 0; nt < 2; ++nt) {
                    acc[mt][nt] = __builtin_amdgcn_mfma_f32_16x16x32_bf16(af[mt], bf[nt], acc[mt][nt], 0, 0, 0);
                }
            }
        }
        __syncthreads();
    }
    #pragma unroll
    for (int mt = 0; mt < 4; ++mt) {
        #pragma unroll
        for (int nt = 0; nt < 2; ++nt) {
            #pragma unroll
            for (int r = 0; r < 4; ++r) {
                int m = wm + mt * 16 + lq * 4 + r;
                int n = wn + nt * 16 + lr;
                out[(size_t)(m0 + m) * DIMSZ + n0 + n] = acc[mt][nt][r];
            }
        }
    }
}

extern "C" void kernel_launch(void* const* d_in, const int* in_sizes, int n_in,
                              void* d_out, int out_size, void* d_ws, size_t ws_size,
                              hipStream_t stream) {
    const float* x      = (const float*)d_in[0];
    const float* gate_w = (const float*)d_in[1];
    const float* w1     = (const float*)d_in[2];
    const float* w2     = (const float*)d_in[3];
    const float* w3     = (const float*)d_in[4];
    const float* sw1    = (const float*)d_in[5];
    const float* sw2    = (const float*)d_in[6];
    const float* sw3    = (const float*)d_in[7];
    float* out = (float*)d_out;

    char* ws = (char*)d_ws;
    const size_t SZ_W13  = (size_t)NEXP * INTERSZ * DIMSZ * 2;  // 18,874,368 B
    const size_t SZ_XBF  = (size_t)TTOK * DIMSZ * 2;            //  4,194,304 B
    const size_t SZ_GATE = (size_t)TTOK * 16 * 4;               //    131,072 B
    u16*   W1b   = (u16*)(ws);
    u16*   W3b   = (u16*)(ws + SZ_W13);
    u16*   W2cat = (u16*)(ws + 2 * SZ_W13);
    u16*   Xbf   = (u16*)(ws + 3 * SZ_W13);
    float* gate  = (float*)(ws + 3 * SZ_W13 + SZ_XBF);
    u16*   H     = (u16*)(ws + 3 * SZ_W13 + SZ_XBF + SZ_GATE);  // [2048][9216] bf16

    cast_w13<<<2048, 256, 0, stream>>>(w1, sw1, W1b);
    cast_w13<<<2048, 256, 0, stream>>>(w3, sw3, W3b);
    cast_w2cat<<<2048, 256, 0, stream>>>(w2, sw2, W2cat);
    gate_kernel<<<TTOK / 4, 256, 0, stream>>>(x, gate_w, gate, Xbf);
    gemm1<<<dim3(INTERSZ / 128, TTOK / 128, NEXP), 256, 0, stream>>>(Xbf, W1b, W3b, gate, H);
    gemm2<<<dim3(DIMSZ / 64, TTOK / 128), 256, 0, stream>>>(H, W2cat, out);
}

// Round 2
// 431.559 us; speedup vs baseline: 1.2333x; 1.2333x over previous
//
#include <hip/hip_runtime.h>
#include <stdint.h>

typedef unsigned short u16;
typedef __bf16 bf16x8 __attribute__((ext_vector_type(8)));
typedef float f32x4 __attribute__((ext_vector_type(4)));

#define TTOK 2048
#define DIMSZ 1024
#define NROUT 16
#define INTERSZ 512

__device__ __forceinline__ u16 f2bf(float f) {
    unsigned int u = __builtin_bit_cast(unsigned int, f);
    unsigned int r = u + 0x7FFFu + ((u >> 16) & 1u);
    return (u16)(r >> 16);
}

__device__ __forceinline__ void gl2lds16(const void* g, void* l) {
    __builtin_amdgcn_global_load_lds(
        (const __attribute__((address_space(1))) void*)(uintptr_t)g,
        (__attribute__((address_space(3))) void*)(uintptr_t)l,
        16, 0, 0);
}

// ---- fp32 -> bf16 cast of concat(a, b) ----
__global__ void cast_concat(const float* __restrict__ a, int na4,
                            const float* __restrict__ b, int nb4,
                            u16* __restrict__ dst) {
    const int n4 = na4 + nb4;
    for (int i = blockIdx.x * blockDim.x + threadIdx.x; i < n4;
         i += gridDim.x * blockDim.x) {
        float4 v = (i < na4) ? ((const float4*)a)[i] : ((const float4*)b)[i - na4];
        ushort4 o;
        o.x = f2bf(v.x); o.y = f2bf(v.y); o.z = f2bf(v.z); o.w = f2bf(v.w);
        *(ushort4*)&dst[(size_t)i * 4] = o;
    }
}

// ---- gate: fp32 scores, sigmoid, top-2; build per-expert token lists; cast x->bf16 ----
__global__ __launch_bounds__(256) void gate_kernel(
    const float* __restrict__ x, const float* __restrict__ gw,
    int* __restrict__ counts, int* __restrict__ tokidx, float* __restrict__ tokw,
    u16* __restrict__ Xbf) {
    int wave = threadIdx.x >> 6, lane = threadIdx.x & 63;
    int t = blockIdx.x * 4 + wave;
    const float* xr = x + (size_t)t * DIMSZ;
    float xv[16];
    #pragma unroll
    for (int j = 0; j < 16; ++j) xv[j] = xr[lane + 64 * j];
    float acc[16];
    #pragma unroll
    for (int e = 0; e < 16; ++e) {
        const float* g = gw + e * DIMSZ;
        float a = 0.f;
        #pragma unroll
        for (int j = 0; j < 16; ++j) a += xv[j] * g[lane + 64 * j];
        acc[e] = a;
    }
    #pragma unroll
    for (int off = 32; off > 0; off >>= 1) {
        #pragma unroll
        for (int e = 0; e < 16; ++e) acc[e] += __shfl_xor(acc[e], off);
    }
    float s[16];
    #pragma unroll
    for (int e = 0; e < 16; ++e) s[e] = 1.f / (1.f + expf(-acc[e]));
    int i0 = 0; float v0 = s[0];
    #pragma unroll
    for (int e = 1; e < 16; ++e) { if (s[e] > v0) { v0 = s[e]; i0 = e; } }
    int i1 = -1; float v1 = -1e30f;
    #pragma unroll
    for (int e = 0; e < 16; ++e) { if (e != i0 && s[e] > v1) { v1 = s[e]; i1 = e; } }
    float inv = 1.f / (v0 + v1);
    if (lane == 0) {
        int s0 = atomicAdd(&counts[i0], 1);
        tokidx[i0 * TTOK + s0] = t; tokw[i0 * TTOK + s0] = v0 * inv;
        int s1 = atomicAdd(&counts[i1], 1);
        tokidx[i1 * TTOK + s1] = t; tokw[i1 * TTOK + s1] = v1 * inv;
    }
    #pragma unroll
    for (int j = 0; j < 16; ++j)
        Xbf[(size_t)t * DIMSZ + lane + 64 * j] = f2bf(xv[j]);
}

// ---- GEMM1 sparse: per expert-chunk e (0..17), gathered token rows ----
// e<16: routed, rows = tokidx[e][m0..]; e>=16: shared chunk (all tokens, weight 1)
// BM=128 BN=128 BK=64, wave tile 64x64, dual accumulators (w1 & w3).
__global__ __launch_bounds__(256) void gemm1s(
    const u16* __restrict__ Xbf, const u16* __restrict__ W1b,
    const u16* __restrict__ W3b, const int* __restrict__ counts,
    const int* __restrict__ tokidx, const float* __restrict__ tokw,
    u16* __restrict__ Hc, u16* __restrict__ Hs) {
    const int e = blockIdx.z;
    const int cnt = (e < NROUT) ? counts[e] : TTOK;
    const int m0 = blockIdx.y * 128;
    if (m0 >= cnt) return;
    const int n0 = blockIdx.x * 128;
    __shared__ u16 As[128 * 64], B1s[128 * 64], B3s[128 * 64];
    const size_t eoff = (size_t)e * INTERSZ * DIMSZ;
    const u16* B1 = W1b + eoff + (size_t)n0 * DIMSZ;
    const u16* B3 = W3b + eoff + (size_t)n0 * DIMSZ;
    const int tid = threadIdx.x;

    int rowi[4], cgsi[4]; size_t arow[4];
    #pragma unroll
    for (int i = 0; i < 4; ++i) {
        int c = tid + i * 256;
        rowi[i] = c >> 3;
        cgsi[i] = ((c & 7) ^ (rowi[i] & 7)) * 8;
        int slot = m0 + rowi[i];
        int g;
        if (e < NROUT) g = (slot < cnt) ? tokidx[e * TTOK + slot] : 0;
        else           g = slot;
        arow[i] = (size_t)g * DIMSZ;
    }
    f32x4 acc1[4][4] = {}; f32x4 acc3[4][4] = {};
    const int wave = tid >> 6, lane = tid & 63;
    const int wm = (wave >> 1) * 64, wn = (wave & 1) * 64;
    const int lr = lane & 15, lq = lane >> 4;

    for (int kt = 0; kt < DIMSZ / 64; ++kt) {
        const int k0 = kt * 64;
        #pragma unroll
        for (int i = 0; i < 4; ++i) {
            int c = tid + i * 256;
            int boff = rowi[i] * DIMSZ + k0 + cgsi[i];
            gl2lds16(Xbf + arow[i] + k0 + cgsi[i], &As[c * 8]);
            gl2lds16(B1 + boff, &B1s[c * 8]);
            gl2lds16(B3 + boff, &B3s[c * 8]);
        }
        __syncthreads();
        #pragma unroll
        for (int ks = 0; ks < 2; ++ks) {
            bf16x8 af[4], b1f[4], b3f[4];
            const int g = lq + ks * 4;
            #pragma unroll
            for (int mt = 0; mt < 4; ++mt) {
                int m = wm + mt * 16 + lr;
                af[mt] = *(const bf16x8*)&As[(m * 8 + (g ^ (m & 7))) * 8];
            }
            #pragma unroll
            for (int nt = 0; nt < 4; ++nt) {
                int n = wn + nt * 16 + lr;
                int ch = (n * 8 + (g ^ (n & 7))) * 8;
                b1f[nt] = *(const bf16x8*)&B1s[ch];
                b3f[nt] = *(const bf16x8*)&B3s[ch];
            }
            #pragma unroll
            for (int mt = 0; mt < 4; ++mt) {
                #pragma unroll
                for (int nt = 0; nt < 4; ++nt) {
                    acc1[mt][nt] = __builtin_amdgcn_mfma_f32_16x16x32_bf16(af[mt], b1f[nt], acc1[mt][nt], 0, 0, 0);
                    acc3[mt][nt] = __builtin_amdgcn_mfma_f32_16x16x32_bf16(af[mt], b3f[nt], acc3[mt][nt], 0, 0, 0);
                }
            }
        }
        __syncthreads();
    }
    #pragma unroll
    for (int mt = 0; mt < 4; ++mt) {
        #pragma unroll
        for (int nt = 0; nt < 4; ++nt) {
            #pragma unroll
            for (int r = 0; r < 4; ++r) {
                int m = wm + mt * 16 + lq * 4 + r;
                int n = wn + nt * 16 + lr;
                int slot = m0 + m;
                bool valid = slot < cnt;
                float h1 = acc1[mt][nt][r], h3 = acc3[mt][nt][r];
                float hv = 0.f;
                if (valid) {
                    float tw = (e < NROUT) ? tokw[e * TTOK + slot] : 1.0f;
                    hv = h1 / (1.f + __expf(-h1)) * h3 * tw;
                }
                if (e < NROUT)
                    Hc[((size_t)e * TTOK + slot) * INTERSZ + n0 + n] = f2bf(hv);
                else
                    Hs[(size_t)slot * DIMSZ + (e - NROUT) * INTERSZ + n0 + n] = f2bf(hv);
            }
        }
    }
}

// ---- GEMM2 shared: out[t,d] = sum_k Hs[t,k] * sw2b[d,k]; dense, plain store ----
__global__ __launch_bounds__(256) void gemm2_shared(
    const u16* __restrict__ Hs, const u16* __restrict__ W2sb,
    float* __restrict__ out) {
    __shared__ u16 As[128 * 64], Bs[64 * 64];
    const int m0 = blockIdx.y * 128, n0 = blockIdx.x * 64;
    const u16* A0 = Hs + (size_t)m0 * DIMSZ;
    const u16* B0 = W2sb + (size_t)n0 * DIMSZ;
    const int tid = threadIdx.x;
    const int wave = tid >> 6, lane = tid & 63;
    const int wm = (wave >> 1) * 64, wn = (wave & 1) * 32;
    const int lr = lane & 15, lq = lane >> 4;

    f32x4 acc[4][2] = {};
    for (int kt = 0; kt < DIMSZ / 64; ++kt) {
        const int k0 = kt * 64;
        #pragma unroll
        for (int i = 0; i < 4; ++i) {
            int c = tid + i * 256;
            int row = c >> 3;
            int cgs = ((c & 7) ^ (row & 7)) * 8;
            gl2lds16(A0 + (size_t)row * DIMSZ + k0 + cgs, &As[c * 8]);
        }
        #pragma unroll
        for (int i = 0; i < 2; ++i) {
            int c = tid + i * 256;
            int row = c >> 3;
            int cgs = ((c & 7) ^ (row & 7)) * 8;
            gl2lds16(B0 + (size_t)row * DIMSZ + k0 + cgs, &Bs[c * 8]);
        }
        __syncthreads();
        #pragma unroll
        for (int ks = 0; ks < 2; ++ks) {
            bf16x8 af[4], bfr[2];
            const int g = lq + ks * 4;
            #pragma unroll
            for (int mt = 0; mt < 4; ++mt) {
                int m = wm + mt * 16 + lr;
                af[mt] = *(const bf16x8*)&As[(m * 8 + (g ^ (m & 7))) * 8];
            }
            #pragma unroll
            for (int nt = 0; nt < 2; ++nt) {
                int n = wn + nt * 16 + lr;
                bfr[nt] = *(const bf16x8*)&Bs[(n * 8 + (g ^ (n & 7))) * 8];
            }
            #pragma unroll
            for (int mt = 0; mt < 4; ++mt) {
                #pragma unroll
                for (int nt = 0; nt < 2; ++nt) {
                    acc[mt][nt] = __builtin_amdgcn_mfma_f32_16x16x32_bf16(af[mt], bfr[nt], acc[mt][nt], 0, 0, 0);
                }
            }
        }
        __syncthreads();
    }
    #pragma unroll
    for (int mt = 0; mt < 4; ++mt) {
        #pragma unroll
        for (int nt = 0; nt < 2; ++nt) {
            #pragma unroll
            for (int r = 0; r < 4; ++r) {
                int m = wm + mt * 16 + lq * 4 + r;
                int n = wn + nt * 16 + lr;
                out[(size_t)(m0 + m) * DIMSZ + n0 + n] = acc[mt][nt][r];
            }
        }
    }
}

// ---- GEMM2 routed: per expert, compacted rows of Hc @ w2[e]^T, scatter-atomicAdd ----
__global__ __launch_bounds__(256) void gemm2_routed(
    const u16* __restrict__ Hc, const u16* __restrict__ W2b,
    const int* __restrict__ counts, const int* __restrict__ tokidx,
    float* __restrict__ out) {
    const int e = blockIdx.z;
    const int cnt = counts[e];
    const int m0 = blockIdx.y * 128;
    if (m0 >= cnt) return;
    const int n0 = blockIdx.x * 64;
    __shared__ u16 As[128 * 64], Bs[64 * 64];
    const u16* A0 = Hc + ((size_t)e * TTOK + m0) * INTERSZ;
    const u16* B0 = W2b + ((size_t)e * DIMSZ + n0) * INTERSZ;
    const int tid = threadIdx.x;
    const int wave = tid >> 6, lane = tid & 63;
    const int wm = (wave >> 1) * 64, wn = (wave & 1) * 32;
    const int lr = lane & 15, lq = lane >> 4;

    f32x4 acc[4][2] = {};
    for (int kt = 0; kt < INTERSZ / 64; ++kt) {
        const int k0 = kt * 64;
        #pragma unroll
        for (int i = 0; i < 4; ++i) {
            int c = tid + i * 256;
            int row = c >> 3;
            int cgs = ((c & 7) ^ (row & 7)) * 8;
            gl2lds16(A0 + (size_t)row * INTERSZ + k0 + cgs, &As[c * 8]);
        }
        #pragma unroll
        for (int i = 0; i < 2; ++i) {
            int c = tid + i * 256;
            int row = c >> 3;
            int cgs = ((c & 7) ^ (row & 7)) * 8;
            gl2lds16(B0 + (size_t)row * INTERSZ + k0 + cgs, &Bs[c * 8]);
        }
        __syncthreads();
        #pragma unroll
        for (int ks = 0; ks < 2; ++ks) {
            bf16x8 af[4], bfr[2];
            const int g = lq + ks * 4;
            #pragma unroll
            for (int mt = 0; mt < 4; ++mt) {
                int m = wm + mt * 16 + lr;
                af[mt] = *(const bf16x8*)&As[(m * 8 + (g ^ (m & 7))) * 8];
            }
            #pragma unroll
            for (int nt = 0; nt < 2; ++nt) {
                int n = wn + nt * 16 + lr;
                bfr[nt] = *(const bf16x8*)&Bs[(n * 8 + (g ^ (n & 7))) * 8];
            }
            #pragma unroll
            for (int mt = 0; mt < 4; ++mt) {
                #pragma unroll
                for (int nt = 0; nt < 2; ++nt) {
                    acc[mt][nt] = __builtin_amdgcn_mfma_f32_16x16x32_bf16(af[mt], bfr[nt], acc[mt][nt], 0, 0, 0);
                }
            }
        }
        __syncthreads();
    }
    #pragma unroll
    for (int mt = 0; mt < 4; ++mt) {
        #pragma unroll
        for (int r = 0; r < 4; ++r) {
            int m = wm + mt * 16 + lq * 4 + r;
            int slot = m0 + m;
            if (slot < cnt) {
                int t = tokidx[e * TTOK + slot];
                #pragma unroll
                for (int nt = 0; nt < 2; ++nt) {
                    int n = wn + nt * 16 + lr;
                    unsafeAtomicAdd(&out[(size_t)t * DIMSZ + n0 + n], acc[mt][nt][r]);
                }
            }
        }
    }
}

extern "C" void kernel_launch(void* const* d_in, const int* in_sizes, int n_in,
                              void* d_out, int out_size, void* d_ws, size_t ws_size,
                              hipStream_t stream) {
    const float* x      = (const float*)d_in[0];
    const float* gate_w = (const float*)d_in[1];
    const float* w1     = (const float*)d_in[2];
    const float* w2     = (const float*)d_in[3];
    const float* w3     = (const float*)d_in[4];
    const float* sw1    = (const float*)d_in[5];
    const float* sw2    = (const float*)d_in[6];
    const float* sw3    = (const float*)d_in[7];
    float* out = (float*)d_out;

    char* ws = (char*)d_ws;
    const size_t SZ_W   = (size_t)(NROUT + 2) * INTERSZ * DIMSZ * 2;  // 18,874,368 B each
    const size_t SZ_XBF = (size_t)TTOK * DIMSZ * 2;
    u16*   W1b    = (u16*)(ws);
    u16*   W3b    = (u16*)(ws + SZ_W);
    u16*   W2all  = (u16*)(ws + 2 * SZ_W);                 // [16][1024][512] ++ [1024][1024]
    u16*   Xbf    = (u16*)(ws + 3 * SZ_W);
    char*  route  = ws + 3 * SZ_W + SZ_XBF;
    int*   counts = (int*)route;                           // 16 ints (zeroed below)
    int*   tokidx = (int*)(route + 256);                   // [16][2048]
    float* tokw   = (float*)(route + 256 + 16 * TTOK * 4); // [16][2048]
    char*  hbuf   = route + 256 + 2 * (size_t)16 * TTOK * 4;
    u16*   Hc     = (u16*)hbuf;                            // [16][2048][512] bf16
    u16*   Hs     = (u16*)(hbuf + (size_t)NROUT * TTOK * INTERSZ * 2); // [2048][1024]
    u16*   W2sb   = W2all + (size_t)NROUT * DIMSZ * INTERSZ;

    const int NA4 = NROUT * INTERSZ * DIMSZ / 4;  // 2,097,152 (same for w1/w3/w2)
    const int NB4 = DIMSZ * DIMSZ / 4;            //   262,144

    hipMemsetAsync(counts, 0, 256, stream);
    cast_concat<<<2048, 256, 0, stream>>>(w1, NA4, sw1, NB4, W1b);
    cast_concat<<<2048, 256, 0, stream>>>(w3, NA4, sw3, NB4, W3b);
    cast_concat<<<2048, 256, 0, stream>>>(w2, NA4, sw2, NB4, W2all);
    gate_kernel<<<TTOK / 4, 256, 0, stream>>>(x, gate_w, counts, tokidx, tokw, Xbf);
    gemm1s<<<dim3(INTERSZ / 128, TTOK / 128, NROUT + 2), 256, 0, stream>>>(
        Xbf, W1b, W3b, counts, tokidx, tokw, Hc, Hs);
    gemm2_shared<<<dim3(DIMSZ / 64, TTOK / 128), 256, 0, stream>>>(Hs, W2sb, out);
    gemm2_routed<<<dim3(DIMSZ / 64, TTOK / 128, NROUT), 256, 0, stream>>>(
        Hc, W2all, counts, tokidx, out);
}

// Round 3
// 391.261 us; speedup vs baseline: 1.3603x; 1.1030x over previous
//
#include <hip/hip_runtime.h>
#include <stdint.h>

typedef unsigned short u16;
typedef __bf16 bf16x8 __attribute__((ext_vector_type(8)));
typedef float f32x4 __attribute__((ext_vector_type(4)));

#define TTOK 2048
#define DIMSZ 1024
#define NROUT 16
#define INTERSZ 512

__device__ __forceinline__ u16 f2bf(float f) {
    unsigned int u = __builtin_bit_cast(unsigned int, f);
    unsigned int r = u + 0x7FFFu + ((u >> 16) & 1u);
    return (u16)(r >> 16);
}

__device__ __forceinline__ void gl2lds16(const void* g, void* l) {
    __builtin_amdgcn_global_load_lds(
        (const __attribute__((address_space(1))) void*)(uintptr_t)g,
        (__attribute__((address_space(3))) void*)(uintptr_t)l,
        16, 0, 0);
}

// ---- fp32 -> bf16 cast of concat(a, b) ----
__global__ void cast_concat(const float* __restrict__ a, int na4,
                            const float* __restrict__ b, int nb4,
                            u16* __restrict__ dst) {
    const int n4 = na4 + nb4;
    for (int i = blockIdx.x * blockDim.x + threadIdx.x; i < n4;
         i += gridDim.x * blockDim.x) {
        float4 v = (i < na4) ? ((const float4*)a)[i] : ((const float4*)b)[i - na4];
        ushort4 o;
        o.x = f2bf(v.x); o.y = f2bf(v.y); o.z = f2bf(v.z); o.w = f2bf(v.w);
        *(ushort4*)&dst[(size_t)i * 4] = o;
    }
}

// ---- gate scores: fp32 sigmoid top-2 per token; NO atomics; also cast x->bf16 ----
__global__ __launch_bounds__(256) void gate_score(
    const float* __restrict__ x, const float* __restrict__ gw,
    int* __restrict__ topi, float2* __restrict__ topw, u16* __restrict__ Xbf) {
    int wave = threadIdx.x >> 6, lane = threadIdx.x & 63;
    int t = blockIdx.x * 4 + wave;
    const float* xr = x + (size_t)t * DIMSZ;
    float xv[16];
    #pragma unroll
    for (int j = 0; j < 16; ++j) xv[j] = xr[lane + 64 * j];
    float acc[16];
    #pragma unroll
    for (int e = 0; e < 16; ++e) {
        const float* g = gw + e * DIMSZ;
        float a = 0.f;
        #pragma unroll
        for (int j = 0; j < 16; ++j) a += xv[j] * g[lane + 64 * j];
        acc[e] = a;
    }
    #pragma unroll
    for (int off = 32; off > 0; off >>= 1) {
        #pragma unroll
        for (int e = 0; e < 16; ++e) acc[e] += __shfl_xor(acc[e], off);
    }
    float s[16];
    #pragma unroll
    for (int e = 0; e < 16; ++e) s[e] = 1.f / (1.f + expf(-acc[e]));
    int i0 = 0; float v0 = s[0];
    #pragma unroll
    for (int e = 1; e < 16; ++e) { if (s[e] > v0) { v0 = s[e]; i0 = e; } }
    int i1 = -1; float v1 = -1e30f;
    #pragma unroll
    for (int e = 0; e < 16; ++e) { if (e != i0 && s[e] > v1) { v1 = s[e]; i1 = e; } }
    float inv = 1.f / (v0 + v1);
    if (lane == 0) {
        topi[t] = i0 | (i1 << 8);
        topw[t] = make_float2(v0 * inv, v1 * inv);
    }
    #pragma unroll
    for (int j = 0; j < 16; ++j)
        Xbf[(size_t)t * DIMSZ + lane + 64 * j] = f2bf(xv[j]);
}

// ---- route: one block per expert; block-wide prefix sum -> ordered compact lists ----
__global__ __launch_bounds__(256) void route_kernel(
    const int* __restrict__ topi, const float2* __restrict__ topw,
    int* __restrict__ counts, int* __restrict__ tokidx, float* __restrict__ tokw) {
    const int e = blockIdx.x;
    const int tid = threadIdx.x;
    int p[8]; int m[8]; int cnt = 0;
    #pragma unroll
    for (int j = 0; j < 8; ++j) {
        int t = tid * 8 + j;
        p[j] = topi[t];
        m[j] = ((p[j] & 255) == e) || ((p[j] >> 8) == e) ? 1 : 0;
        cnt += m[j];
    }
    const int lane = tid & 63, wave = tid >> 6;
    int v = cnt;
    #pragma unroll
    for (int off = 1; off < 64; off <<= 1) {
        int u = __shfl_up(v, off);
        if (lane >= off) v += u;
    }
    __shared__ int wsum[4];
    if (lane == 63) wsum[wave] = v;
    __syncthreads();
    int wbase = 0;
    #pragma unroll
    for (int w = 0; w < 4; ++w) wbase += (w < wave) ? wsum[w] : 0;
    int base = wbase + v - cnt;  // exclusive prefix
    #pragma unroll
    for (int j = 0; j < 8; ++j) {
        if (m[j]) {
            int t = tid * 8 + j;
            float2 w2 = topw[t];
            tokidx[e * TTOK + base] = t;
            tokw[e * TTOK + base] = ((p[j] & 255) == e) ? w2.x : w2.y;
            ++base;
        }
    }
    if (tid == 0) counts[e] = wsum[0] + wsum[1] + wsum[2] + wsum[3];
}

// ---- GEMM1 sparse: per expert-chunk e (0..17), gathered token rows ----
__global__ __launch_bounds__(256) void gemm1s(
    const u16* __restrict__ Xbf, const u16* __restrict__ W1b,
    const u16* __restrict__ W3b, const int* __restrict__ counts,
    const int* __restrict__ tokidx, const float* __restrict__ tokw,
    u16* __restrict__ Hc, u16* __restrict__ Hs) {
    const int e = blockIdx.z;
    const int cnt = (e < NROUT) ? counts[e] : TTOK;
    const int m0 = blockIdx.y * 128;
    if (m0 >= cnt) return;
    const int n0 = blockIdx.x * 128;
    __shared__ u16 As[128 * 64], B1s[128 * 64], B3s[128 * 64];
    const size_t eoff = (size_t)e * INTERSZ * DIMSZ;
    const u16* B1 = W1b + eoff + (size_t)n0 * DIMSZ;
    const u16* B3 = W3b + eoff + (size_t)n0 * DIMSZ;
    const int tid = threadIdx.x;

    int rowi[4], cgsi[4]; size_t arow[4];
    #pragma unroll
    for (int i = 0; i < 4; ++i) {
        int c = tid + i * 256;
        rowi[i] = c >> 3;
        cgsi[i] = ((c & 7) ^ (rowi[i] & 7)) * 8;
        int slot = m0 + rowi[i];
        int g;
        if (e < NROUT) g = (slot < cnt) ? tokidx[e * TTOK + slot] : 0;
        else           g = slot;
        arow[i] = (size_t)g * DIMSZ;
    }
    f32x4 acc1[4][4] = {}; f32x4 acc3[4][4] = {};
    const int wave = tid >> 6, lane = tid & 63;
    const int wm = (wave >> 1) * 64, wn = (wave & 1) * 64;
    const int lr = lane & 15, lq = lane >> 4;

    for (int kt = 0; kt < DIMSZ / 64; ++kt) {
        const int k0 = kt * 64;
        #pragma unroll
        for (int i = 0; i < 4; ++i) {
            int c = tid + i * 256;
            int boff = rowi[i] * DIMSZ + k0 + cgsi[i];
            gl2lds16(Xbf + arow[i] + k0 + cgsi[i], &As[c * 8]);
            gl2lds16(B1 + boff, &B1s[c * 8]);
            gl2lds16(B3 + boff, &B3s[c * 8]);
        }
        __syncthreads();
        #pragma unroll
        for (int ks = 0; ks < 2; ++ks) {
            bf16x8 af[4], b1f[4], b3f[4];
            const int g = lq + ks * 4;
            #pragma unroll
            for (int mt = 0; mt < 4; ++mt) {
                int m = wm + mt * 16 + lr;
                af[mt] = *(const bf16x8*)&As[(m * 8 + (g ^ (m & 7))) * 8];
            }
            #pragma unroll
            for (int nt = 0; nt < 4; ++nt) {
                int n = wn + nt * 16 + lr;
                int ch = (n * 8 + (g ^ (n & 7))) * 8;
                b1f[nt] = *(const bf16x8*)&B1s[ch];
                b3f[nt] = *(const bf16x8*)&B3s[ch];
            }
            #pragma unroll
            for (int mt = 0; mt < 4; ++mt) {
                #pragma unroll
                for (int nt = 0; nt < 4; ++nt) {
                    acc1[mt][nt] = __builtin_amdgcn_mfma_f32_16x16x32_bf16(af[mt], b1f[nt], acc1[mt][nt], 0, 0, 0);
                    acc3[mt][nt] = __builtin_amdgcn_mfma_f32_16x16x32_bf16(af[mt], b3f[nt], acc3[mt][nt], 0, 0, 0);
                }
            }
        }
        __syncthreads();
    }
    #pragma unroll
    for (int mt = 0; mt < 4; ++mt) {
        #pragma unroll
        for (int nt = 0; nt < 4; ++nt) {
            #pragma unroll
            for (int r = 0; r < 4; ++r) {
                int m = wm + mt * 16 + lq * 4 + r;
                int n = wn + nt * 16 + lr;
                int slot = m0 + m;
                bool valid = slot < cnt;
                float h1 = acc1[mt][nt][r], h3 = acc3[mt][nt][r];
                float hv = 0.f;
                if (valid) {
                    float tw = (e < NROUT) ? tokw[e * TTOK + slot] : 1.0f;
                    hv = h1 / (1.f + __expf(-h1)) * h3 * tw;
                }
                if (e < NROUT)
                    Hc[((size_t)e * TTOK + slot) * INTERSZ + n0 + n] = f2bf(hv);
                else
                    Hs[(size_t)slot * DIMSZ + (e - NROUT) * INTERSZ + n0 + n] = f2bf(hv);
            }
        }
    }
}

// ---- GEMM2 shared: out[t,d] = sum_k Hs[t,k] * sw2b[d,k]; dense, plain store ----
__global__ __launch_bounds__(256) void gemm2_shared(
    const u16* __restrict__ Hs, const u16* __restrict__ W2sb,
    float* __restrict__ out) {
    __shared__ u16 As[128 * 64], Bs[64 * 64];
    const int m0 = blockIdx.y * 128, n0 = blockIdx.x * 64;
    const u16* A0 = Hs + (size_t)m0 * DIMSZ;
    const u16* B0 = W2sb + (size_t)n0 * DIMSZ;
    const int tid = threadIdx.x;
    const int wave = tid >> 6, lane = tid & 63;
    const int wm = (wave >> 1) * 64, wn = (wave & 1) * 32;
    const int lr = lane & 15, lq = lane >> 4;

    f32x4 acc[4][2] = {};
    for (int kt = 0; kt < DIMSZ / 64; ++kt) {
        const int k0 = kt * 64;
        #pragma unroll
        for (int i = 0; i < 4; ++i) {
            int c = tid + i * 256;
            int row = c >> 3;
            int cgs = ((c & 7) ^ (row & 7)) * 8;
            gl2lds16(A0 + (size_t)row * DIMSZ + k0 + cgs, &As[c * 8]);
        }
        #pragma unroll
        for (int i = 0; i < 2; ++i) {
            int c = tid + i * 256;
            int row = c >> 3;
            int cgs = ((c & 7) ^ (row & 7)) * 8;
            gl2lds16(B0 + (size_t)row * DIMSZ + k0 + cgs, &Bs[c * 8]);
        }
        __syncthreads();
        #pragma unroll
        for (int ks = 0; ks < 2; ++ks) {
            bf16x8 af[4], bfr[2];
            const int g = lq + ks * 4;
            #pragma unroll
            for (int mt = 0; mt < 4; ++mt) {
                int m = wm + mt * 16 + lr;
                af[mt] = *(const bf16x8*)&As[(m * 8 + (g ^ (m & 7))) * 8];
            }
            #pragma unroll
            for (int nt = 0; nt < 2; ++nt) {
                int n = wn + nt * 16 + lr;
                bfr[nt] = *(const bf16x8*)&Bs[(n * 8 + (g ^ (n & 7))) * 8];
            }
            #pragma unroll
            for (int mt = 0; mt < 4; ++mt) {
                #pragma unroll
                for (int nt = 0; nt < 2; ++nt) {
                    acc[mt][nt] = __builtin_amdgcn_mfma_f32_16x16x32_bf16(af[mt], bfr[nt], acc[mt][nt], 0, 0, 0);
                }
            }
        }
        __syncthreads();
    }
    #pragma unroll
    for (int mt = 0; mt < 4; ++mt) {
        #pragma unroll
        for (int nt = 0; nt < 2; ++nt) {
            #pragma unroll
            for (int r = 0; r < 4; ++r) {
                int m = wm + mt * 16 + lq * 4 + r;
                int n = wn + nt * 16 + lr;
                out[(size_t)(m0 + m) * DIMSZ + n0 + n] = acc[mt][nt][r];
            }
        }
    }
}

// ---- GEMM2 routed: per expert, compacted rows of Hc @ w2[e]^T, scatter-atomicAdd ----
__global__ __launch_bounds__(256) void gemm2_routed(
    const u16* __restrict__ Hc, const u16* __restrict__ W2b,
    const int* __restrict__ counts, const int* __restrict__ tokidx,
    float* __restrict__ out) {
    const int e = blockIdx.z;
    const int cnt = counts[e];
    const int m0 = blockIdx.y * 128;
    if (m0 >= cnt) return;
    const int n0 = blockIdx.x * 64;
    __shared__ u16 As[128 * 64], Bs[64 * 64];
    const u16* A0 = Hc + ((size_t)e * TTOK + m0) * INTERSZ;
    const u16* B0 = W2b + ((size_t)e * DIMSZ + n0) * INTERSZ;
    const int tid = threadIdx.x;
    const int wave = tid >> 6, lane = tid & 63;
    const int wm = (wave >> 1) * 64, wn = (wave & 1) * 32;
    const int lr = lane & 15, lq = lane >> 4;

    f32x4 acc[4][2] = {};
    for (int kt = 0; kt < INTERSZ / 64; ++kt) {
        const int k0 = kt * 64;
        #pragma unroll
        for (int i = 0; i < 4; ++i) {
            int c = tid + i * 256;
            int row = c >> 3;
            int cgs = ((c & 7) ^ (row & 7)) * 8;
            gl2lds16(A0 + (size_t)row * INTERSZ + k0 + cgs, &As[c * 8]);
        }
        #pragma unroll
        for (int i = 0; i < 2; ++i) {
            int c = tid + i * 256;
            int row = c >> 3;
            int cgs = ((c & 7) ^ (row & 7)) * 8;
            gl2lds16(B0 + (size_t)row * INTERSZ + k0 + cgs, &Bs[c * 8]);
        }
        __syncthreads();
        #pragma unroll
        for (int ks = 0; ks < 2; ++ks) {
            bf16x8 af[4], bfr[2];
            const int g = lq + ks * 4;
            #pragma unroll
            for (int mt = 0; mt < 4; ++mt) {
                int m = wm + mt * 16 + lr;
                af[mt] = *(const bf16x8*)&As[(m * 8 + (g ^ (m & 7))) * 8];
            }
            #pragma unroll
            for (int nt = 0; nt < 2; ++nt) {
                int n = wn + nt * 16 + lr;
                bfr[nt] = *(const bf16x8*)&Bs[(n * 8 + (g ^ (n & 7))) * 8];
            }
            #pragma unroll
            for (int mt = 0; mt < 4; ++mt) {
                #pragma unroll
                for (int nt = 0; nt < 2; ++nt) {
                    acc[mt][nt] = __builtin_amdgcn_mfma_f32_16x16x32_bf16(af[mt], bfr[nt], acc[mt][nt], 0, 0, 0);
                }
            }
        }
        __syncthreads();
    }
    #pragma unroll
    for (int mt = 0; mt < 4; ++mt) {
        #pragma unroll
        for (int r = 0; r < 4; ++r) {
            int m = wm + mt * 16 + lq * 4 + r;
            int slot = m0 + m;
            if (slot < cnt) {
                int t = tokidx[e * TTOK + slot];
                #pragma unroll
                for (int nt = 0; nt < 2; ++nt) {
                    int n = wn + nt * 16 + lr;
                    unsafeAtomicAdd(&out[(size_t)t * DIMSZ + n0 + n], acc[mt][nt][r]);
                }
            }
        }
    }
}

extern "C" void kernel_launch(void* const* d_in, const int* in_sizes, int n_in,
                              void* d_out, int out_size, void* d_ws, size_t ws_size,
                              hipStream_t stream) {
    const float* x      = (const float*)d_in[0];
    const float* gate_w = (const float*)d_in[1];
    const float* w1     = (const float*)d_in[2];
    const float* w2     = (const float*)d_in[3];
    const float* w3     = (const float*)d_in[4];
    const float* sw1    = (const float*)d_in[5];
    const float* sw2    = (const float*)d_in[6];
    const float* sw3    = (const float*)d_in[7];
    float* out = (float*)d_out;

    char* ws = (char*)d_ws;
    const size_t SZ_W   = (size_t)(NROUT + 2) * INTERSZ * DIMSZ * 2;  // 18,874,368 B each
    const size_t SZ_XBF = (size_t)TTOK * DIMSZ * 2;
    u16*   W1b    = (u16*)(ws);
    u16*   W3b    = (u16*)(ws + SZ_W);
    u16*   W2all  = (u16*)(ws + 2 * SZ_W);                 // [16][1024][512] ++ [1024][1024]
    u16*   Xbf    = (u16*)(ws + 3 * SZ_W);
    char*  route  = ws + 3 * SZ_W + SZ_XBF;
    int*   counts = (int*)route;                           // 16 ints
    int*   topi   = (int*)(route + 256);                   // [2048]
    float2* topw  = (float2*)(route + 256 + TTOK * 4);     // [2048]
    int*   tokidx = (int*)(route + 256 + TTOK * 12);       // [16][2048]
    float* tokw   = (float*)(route + 256 + TTOK * 12 + 16 * TTOK * 4); // [16][2048]
    char*  hbuf   = route + 256 + TTOK * 12 + 2 * (size_t)16 * TTOK * 4;
    u16*   Hc     = (u16*)hbuf;                            // [16][2048][512] bf16
    u16*   Hs     = (u16*)(hbuf + (size_t)NROUT * TTOK * INTERSZ * 2); // [2048][1024]
    u16*   W2sb   = W2all + (size_t)NROUT * DIMSZ * INTERSZ;

    const int NA4 = NROUT * INTERSZ * DIMSZ / 4;  // 2,097,152 (same for w1/w3/w2)
    const int NB4 = DIMSZ * DIMSZ / 4;            //   262,144

    cast_concat<<<2048, 256, 0, stream>>>(w1, NA4, sw1, NB4, W1b);
    cast_concat<<<2048, 256, 0, stream>>>(w3, NA4, sw3, NB4, W3b);
    cast_concat<<<2048, 256, 0, stream>>>(w2, NA4, sw2, NB4, W2all);
    gate_score<<<TTOK / 4, 256, 0, stream>>>(x, gate_w, topi, topw, Xbf);
    route_kernel<<<NROUT, 256, 0, stream>>>(topi, topw, counts, tokidx, tokw);
    gemm1s<<<dim3(INTERSZ / 128, TTOK / 128, NROUT + 2), 256, 0, stream>>>(
        Xbf, W1b, W3b, counts, tokidx, tokw, Hc, Hs);
    gemm2_shared<<<dim3(DIMSZ / 64, TTOK / 128), 256, 0, stream>>>(Hs, W2sb, out);
    gemm2_routed<<<dim3(DIMSZ / 64, TTOK / 128, NROUT), 256, 0, stream>>>(
        Hc, W2all, counts, tokidx, out);
}

// Round 4
// 313.827 us; speedup vs baseline: 1.6959x; 1.2467x over previous
//
#include <hip/hip_runtime.h>
#include <stdint.h>

typedef unsigned short u16;
typedef __bf16 bf16x8 __attribute__((ext_vector_type(8)));
typedef float f32x4 __attribute__((ext_vector_type(4)));

#define TTOK 2048
#define DIMSZ 1024
#define NROUT 16
#define INTERSZ 512

__device__ __forceinline__ u16 f2bf(float f) {
    unsigned int u = __builtin_bit_cast(unsigned int, f);
    unsigned int r = u + 0x7FFFu + ((u >> 16) & 1u);
    return (u16)(r >> 16);
}

__device__ __forceinline__ void gl2lds16(const void* g, void* l) {
    __builtin_amdgcn_global_load_lds(
        (const __attribute__((address_space(1))) void*)(uintptr_t)g,
        (__attribute__((address_space(3))) void*)(uintptr_t)l,
        16, 0, 0);
}

// ---- one-dispatch fp32->bf16 cast of (w1|sw1), (w3|sw3), (w2|sw2) ----
#define NA4 (NROUT * INTERSZ * DIMSZ / 4)   // 2,097,152 float4 per routed tensor
#define NB4 (DIMSZ * DIMSZ / 4)             //   262,144 float4 per shared tensor
#define NR4 (NA4 + NB4)                     // 2,359,296 per group
__global__ void cast_all(const float* __restrict__ w1, const float* __restrict__ sw1,
                         const float* __restrict__ w3, const float* __restrict__ sw3,
                         const float* __restrict__ w2, const float* __restrict__ sw2,
                         u16* __restrict__ W1b, u16* __restrict__ W3b,
                         u16* __restrict__ W2b) {
    const int n4 = 3 * NR4;
    for (int i = blockIdx.x * blockDim.x + threadIdx.x; i < n4;
         i += gridDim.x * blockDim.x) {
        int r = i / NR4;            // 0,1,2 (const-div)
        int j = i - r * NR4;
        const float* a; const float* b; u16* d;
        if (r == 0)      { a = w1; b = sw1; d = W1b; }
        else if (r == 1) { a = w3; b = sw3; d = W3b; }
        else             { a = w2; b = sw2; d = W2b; }
        float4 v = (j < NA4) ? ((const float4*)a)[j] : ((const float4*)b)[j - NA4];
        ushort4 o;
        o.x = f2bf(v.x); o.y = f2bf(v.y); o.z = f2bf(v.z); o.w = f2bf(v.w);
        *(ushort4*)&d[(size_t)j * 4] = o;
    }
}

// ---- gate scores: fp32 sigmoid top-2 per token; no atomics; also cast x->bf16 ----
__global__ __launch_bounds__(256) void gate_score(
    const float* __restrict__ x, const float* __restrict__ gw,
    int* __restrict__ topi, float2* __restrict__ topw, u16* __restrict__ Xbf) {
    int wave = threadIdx.x >> 6, lane = threadIdx.x & 63;
    int t = blockIdx.x * 4 + wave;
    const float* xr = x + (size_t)t * DIMSZ;
    float xv[16];
    #pragma unroll
    for (int j = 0; j < 16; ++j) xv[j] = xr[lane + 64 * j];
    float acc[16];
    #pragma unroll
    for (int e = 0; e < 16; ++e) {
        const float* g = gw + e * DIMSZ;
        float a = 0.f;
        #pragma unroll
        for (int j = 0; j < 16; ++j) a += xv[j] * g[lane + 64 * j];
        acc[e] = a;
    }
    #pragma unroll
    for (int off = 32; off > 0; off >>= 1) {
        #pragma unroll
        for (int e = 0; e < 16; ++e) acc[e] += __shfl_xor(acc[e], off);
    }
    float s[16];
    #pragma unroll
    for (int e = 0; e < 16; ++e) s[e] = 1.f / (1.f + expf(-acc[e]));
    int i0 = 0; float v0 = s[0];
    #pragma unroll
    for (int e = 1; e < 16; ++e) { if (s[e] > v0) { v0 = s[e]; i0 = e; } }
    int i1 = -1; float v1 = -1e30f;
    #pragma unroll
    for (int e = 0; e < 16; ++e) { if (e != i0 && s[e] > v1) { v1 = s[e]; i1 = e; } }
    float inv = 1.f / (v0 + v1);
    if (lane == 0) {
        topi[t] = i0 | (i1 << 8);
        topw[t] = make_float2(v0 * inv, v1 * inv);
    }
    #pragma unroll
    for (int j = 0; j < 16; ++j)
        Xbf[(size_t)t * DIMSZ + lane + 64 * j] = f2bf(xv[j]);
}

// ---- route: one block per expert; block-wide prefix sum -> ordered compact lists ----
__global__ __launch_bounds__(256) void route_kernel(
    const int* __restrict__ topi, const float2* __restrict__ topw,
    int* __restrict__ counts, int* __restrict__ tokidx, float* __restrict__ tokw) {
    const int e = blockIdx.x;
    const int tid = threadIdx.x;
    int p[8]; int m[8]; int cnt = 0;
    #pragma unroll
    for (int j = 0; j < 8; ++j) {
        int t = tid * 8 + j;
        p[j] = topi[t];
        m[j] = ((p[j] & 255) == e) || ((p[j] >> 8) == e) ? 1 : 0;
        cnt += m[j];
    }
    const int lane = tid & 63, wave = tid >> 6;
    int v = cnt;
    #pragma unroll
    for (int off = 1; off < 64; off <<= 1) {
        int u = __shfl_up(v, off);
        if (lane >= off) v += u;
    }
    __shared__ int wsum[4];
    if (lane == 63) wsum[wave] = v;
    __syncthreads();
    int wbase = 0;
    #pragma unroll
    for (int w = 0; w < 4; ++w) wbase += (w < wave) ? wsum[w] : 0;
    int base = wbase + v - cnt;  // exclusive prefix
    #pragma unroll
    for (int j = 0; j < 8; ++j) {
        if (m[j]) {
            int t = tid * 8 + j;
            float2 w2 = topw[t];
            tokidx[e * TTOK + base] = t;
            tokw[e * TTOK + base] = ((p[j] & 255) == e) ? w2.x : w2.y;
            ++base;
        }
    }
    if (tid == 0) counts[e] = wsum[0] + wsum[1] + wsum[2] + wsum[3];
}

// ---- GEMM1 sparse: BM=64 BN=64 BK=64, 4 waves (2x2, 32x32 wave tile) ----
// e<16: routed (gathered rows), e>=16: shared chunk (all tokens, weight 1)
__global__ __launch_bounds__(256) void gemm1s(
    const u16* __restrict__ Xbf, const u16* __restrict__ W1b,
    const u16* __restrict__ W3b, const int* __restrict__ counts,
    const int* __restrict__ tokidx, const float* __restrict__ tokw,
    u16* __restrict__ Hc, u16* __restrict__ Hs) {
    const int e = blockIdx.z;
    const int cnt = (e < NROUT) ? counts[e] : TTOK;
    const int m0 = blockIdx.y * 64;
    if (m0 >= cnt) return;
    const int n0 = blockIdx.x * 64;
    __shared__ u16 As[64 * 64], B1s[64 * 64], B3s[64 * 64];
    const size_t eoff = (size_t)e * INTERSZ * DIMSZ;
    const u16* B1 = W1b + eoff + (size_t)n0 * DIMSZ;
    const u16* B3 = W3b + eoff + (size_t)n0 * DIMSZ;
    const int tid = threadIdx.x;

    int rowi[2], cgsi[2]; size_t arow[2];
    #pragma unroll
    for (int i = 0; i < 2; ++i) {
        int c = tid + i * 256;
        rowi[i] = c >> 3;
        cgsi[i] = ((c & 7) ^ (rowi[i] & 7)) * 8;
        int slot = m0 + rowi[i];
        int g;
        if (e < NROUT) g = (slot < cnt) ? tokidx[e * TTOK + slot] : 0;
        else           g = slot;
        arow[i] = (size_t)g * DIMSZ;
    }
    f32x4 acc1[2][2] = {}; f32x4 acc3[2][2] = {};
    const int wave = tid >> 6, lane = tid & 63;
    const int wm = (wave >> 1) * 32, wn = (wave & 1) * 32;
    const int lr = lane & 15, lq = lane >> 4;

    for (int kt = 0; kt < DIMSZ / 64; ++kt) {
        const int k0 = kt * 64;
        #pragma unroll
        for (int i = 0; i < 2; ++i) {
            int c = tid + i * 256;
            int boff = rowi[i] * DIMSZ + k0 + cgsi[i];
            gl2lds16(Xbf + arow[i] + k0 + cgsi[i], &As[c * 8]);
            gl2lds16(B1 + boff, &B1s[c * 8]);
            gl2lds16(B3 + boff, &B3s[c * 8]);
        }
        __syncthreads();
        #pragma unroll
        for (int ks = 0; ks < 2; ++ks) {
            bf16x8 af[2], b1f[2], b3f[2];
            const int g = lq + ks * 4;
            #pragma unroll
            for (int mt = 0; mt < 2; ++mt) {
                int m = wm + mt * 16 + lr;
                af[mt] = *(const bf16x8*)&As[(m * 8 + (g ^ (m & 7))) * 8];
            }
            #pragma unroll
            for (int nt = 0; nt < 2; ++nt) {
                int n = wn + nt * 16 + lr;
                int ch = (n * 8 + (g ^ (n & 7))) * 8;
                b1f[nt] = *(const bf16x8*)&B1s[ch];
                b3f[nt] = *(const bf16x8*)&B3s[ch];
            }
            #pragma unroll
            for (int mt = 0; mt < 2; ++mt) {
                #pragma unroll
                for (int nt = 0; nt < 2; ++nt) {
                    acc1[mt][nt] = __builtin_amdgcn_mfma_f32_16x16x32_bf16(af[mt], b1f[nt], acc1[mt][nt], 0, 0, 0);
                    acc3[mt][nt] = __builtin_amdgcn_mfma_f32_16x16x32_bf16(af[mt], b3f[nt], acc3[mt][nt], 0, 0, 0);
                }
            }
        }
        __syncthreads();
    }
    #pragma unroll
    for (int mt = 0; mt < 2; ++mt) {
        #pragma unroll
        for (int nt = 0; nt < 2; ++nt) {
            #pragma unroll
            for (int r = 0; r < 4; ++r) {
                int m = wm + mt * 16 + lq * 4 + r;
                int n = wn + nt * 16 + lr;
                int slot = m0 + m;
                bool valid = slot < cnt;
                float h1 = acc1[mt][nt][r], h3 = acc3[mt][nt][r];
                float hv = 0.f;
                if (valid) {
                    float tw = (e < NROUT) ? tokw[e * TTOK + slot] : 1.0f;
                    hv = h1 / (1.f + __expf(-h1)) * h3 * tw;
                }
                if (e < NROUT)
                    Hc[((size_t)e * TTOK + slot) * INTERSZ + n0 + n] = f2bf(hv);
                else
                    Hs[(size_t)slot * DIMSZ + (e - NROUT) * INTERSZ + n0 + n] = f2bf(hv);
            }
        }
    }
}

// ---- GEMM2 shared: out[t,d] = Hs[t,:] . W2sb[d,:]; BM=64 BN=64, plain store ----
__global__ __launch_bounds__(256) void gemm2_shared(
    const u16* __restrict__ Hs, const u16* __restrict__ W2sb,
    float* __restrict__ out) {
    __shared__ u16 As[64 * 64], Bs[64 * 64];
    const int m0 = blockIdx.y * 64, n0 = blockIdx.x * 64;
    const u16* A0 = Hs + (size_t)m0 * DIMSZ;
    const u16* B0 = W2sb + (size_t)n0 * DIMSZ;
    const int tid = threadIdx.x;
    const int wave = tid >> 6, lane = tid & 63;
    const int wm = (wave >> 1) * 32, wn = (wave & 1) * 32;
    const int lr = lane & 15, lq = lane >> 4;

    f32x4 acc[2][2] = {};
    for (int kt = 0; kt < DIMSZ / 64; ++kt) {
        const int k0 = kt * 64;
        #pragma unroll
        for (int i = 0; i < 2; ++i) {
            int c = tid + i * 256;
            int row = c >> 3;
            int cgs = ((c & 7) ^ (row & 7)) * 8;
            gl2lds16(A0 + (size_t)row * DIMSZ + k0 + cgs, &As[c * 8]);
            gl2lds16(B0 + (size_t)row * DIMSZ + k0 + cgs, &Bs[c * 8]);
        }
        __syncthreads();
        #pragma unroll
        for (int ks = 0; ks < 2; ++ks) {
            bf16x8 af[2], bfr[2];
            const int g = lq + ks * 4;
            #pragma unroll
            for (int mt = 0; mt < 2; ++mt) {
                int m = wm + mt * 16 + lr;
                af[mt] = *(const bf16x8*)&As[(m * 8 + (g ^ (m & 7))) * 8];
            }
            #pragma unroll
            for (int nt = 0; nt < 2; ++nt) {
                int n = wn + nt * 16 + lr;
                bfr[nt] = *(const bf16x8*)&Bs[(n * 8 + (g ^ (n & 7))) * 8];
            }
            #pragma unroll
            for (int mt = 0; mt < 2; ++mt) {
                #pragma unroll
                for (int nt = 0; nt < 2; ++nt) {
                    acc[mt][nt] = __builtin_amdgcn_mfma_f32_16x16x32_bf16(af[mt], bfr[nt], acc[mt][nt], 0, 0, 0);
                }
            }
        }
        __syncthreads();
    }
    #pragma unroll
    for (int mt = 0; mt < 2; ++mt) {
        #pragma unroll
        for (int nt = 0; nt < 2; ++nt) {
            #pragma unroll
            for (int r = 0; r < 4; ++r) {
                int m = wm + mt * 16 + lq * 4 + r;
                int n = wn + nt * 16 + lr;
                out[(size_t)(m0 + m) * DIMSZ + n0 + n] = acc[mt][nt][r];
            }
        }
    }
}

// ---- GEMM2 routed: BM=64 BN=64, compacted Hc rows @ w2[e]^T, scatter-atomicAdd ----
__global__ __launch_bounds__(256) void gemm2_routed(
    const u16* __restrict__ Hc, const u16* __restrict__ W2b,
    const int* __restrict__ counts, const int* __restrict__ tokidx,
    float* __restrict__ out) {
    const int e = blockIdx.z;
    const int cnt = counts[e];
    const int m0 = blockIdx.y * 64;
    if (m0 >= cnt) return;
    const int n0 = blockIdx.x * 64;
    __shared__ u16 As[64 * 64], Bs[64 * 64];
    const u16* A0 = Hc + ((size_t)e * TTOK + m0) * INTERSZ;
    const u16* B0 = W2b + ((size_t)e * DIMSZ + n0) * INTERSZ;
    const int tid = threadIdx.x;
    const int wave = tid >> 6, lane = tid & 63;
    const int wm = (wave >> 1) * 32, wn = (wave & 1) * 32;
    const int lr = lane & 15, lq = lane >> 4;

    f32x4 acc[2][2] = {};
    for (int kt = 0; kt < INTERSZ / 64; ++kt) {
        const int k0 = kt * 64;
        #pragma unroll
        for (int i = 0; i < 2; ++i) {
            int c = tid + i * 256;
            int row = c >> 3;
            int cgs = ((c & 7) ^ (row & 7)) * 8;
            gl2lds16(A0 + (size_t)row * INTERSZ + k0 + cgs, &As[c * 8]);
            gl2lds16(B0 + (size_t)row * INTERSZ + k0 + cgs, &Bs[c * 8]);
        }
        __syncthreads();
        #pragma unroll
        for (int ks = 0; ks < 2; ++ks) {
            bf16x8 af[2], bfr[2];
            const int g = lq + ks * 4;
            #pragma unroll
            for (int mt = 0; mt < 2; ++mt) {
                int m = wm + mt * 16 + lr;
                af[mt] = *(const bf16x8*)&As[(m * 8 + (g ^ (m & 7))) * 8];
            }
            #pragma unroll
            for (int nt = 0; nt < 2; ++nt) {
                int n = wn + nt * 16 + lr;
                bfr[nt] = *(const bf16x8*)&Bs[(n * 8 + (g ^ (n & 7))) * 8];
            }
            #pragma unroll
            for (int mt = 0; mt < 2; ++mt) {
                #pragma unroll
                for (int nt = 0; nt < 2; ++nt) {
                    acc[mt][nt] = __builtin_amdgcn_mfma_f32_16x16x32_bf16(af[mt], bfr[nt], acc[mt][nt], 0, 0, 0);
                }
            }
        }
        __syncthreads();
    }
    #pragma unroll
    for (int mt = 0; mt < 2; ++mt) {
        #pragma unroll
        for (int r = 0; r < 4; ++r) {
            int m = wm + mt * 16 + lq * 4 + r;
            int slot = m0 + m;
            if (slot < cnt) {
                int t = tokidx[e * TTOK + slot];
                #pragma unroll
                for (int nt = 0; nt < 2; ++nt) {
                    int n = wn + nt * 16 + lr;
                    unsafeAtomicAdd(&out[(size_t)t * DIMSZ + n0 + n], acc[mt][nt][r]);
                }
            }
        }
    }
}

extern "C" void kernel_launch(void* const* d_in, const int* in_sizes, int n_in,
                              void* d_out, int out_size, void* d_ws, size_t ws_size,
                              hipStream_t stream) {
    const float* x      = (const float*)d_in[0];
    const float* gate_w = (const float*)d_in[1];
    const float* w1     = (const float*)d_in[2];
    const float* w2     = (const float*)d_in[3];
    const float* w3     = (const float*)d_in[4];
    const float* sw1    = (const float*)d_in[5];
    const float* sw2    = (const float*)d_in[6];
    const float* sw3    = (const float*)d_in[7];
    float* out = (float*)d_out;

    char* ws = (char*)d_ws;
    const size_t SZ_W   = (size_t)(NROUT + 2) * INTERSZ * DIMSZ * 2;  // 18,874,368 B each
    const size_t SZ_XBF = (size_t)TTOK * DIMSZ * 2;
    u16*   W1b    = (u16*)(ws);
    u16*   W3b    = (u16*)(ws + SZ_W);
    u16*   W2all  = (u16*)(ws + 2 * SZ_W);                 // [16][1024][512] ++ [1024][1024]
    u16*   Xbf    = (u16*)(ws + 3 * SZ_W);
    char*  route  = ws + 3 * SZ_W + SZ_XBF;
    int*   counts = (int*)route;                           // 16 ints
    int*   topi   = (int*)(route + 256);                   // [2048]
    float2* topw  = (float2*)(route + 256 + TTOK * 4);     // [2048]
    int*   tokidx = (int*)(route + 256 + TTOK * 12);       // [16][2048]
    float* tokw   = (float*)(route + 256 + TTOK * 12 + 16 * TTOK * 4); // [16][2048]
    char*  hbuf   = route + 256 + TTOK * 12 + 2 * (size_t)16 * TTOK * 4;
    u16*   Hc     = (u16*)hbuf;                            // [16][2048][512] bf16
    u16*   Hs     = (u16*)(hbuf + (size_t)NROUT * TTOK * INTERSZ * 2); // [2048][1024]
    u16*   W2sb   = W2all + (size_t)NROUT * DIMSZ * INTERSZ;

    cast_all<<<8192, 256, 0, stream>>>(w1, sw1, w3, sw3, w2, sw2, W1b, W3b, W2all);
    gate_score<<<TTOK / 4, 256, 0, stream>>>(x, gate_w, topi, topw, Xbf);
    route_kernel<<<NROUT, 256, 0, stream>>>(topi, topw, counts, tokidx, tokw);
    gemm1s<<<dim3(INTERSZ / 64, TTOK / 64, NROUT + 2), 256, 0, stream>>>(
        Xbf, W1b, W3b, counts, tokidx, tokw, Hc, Hs);
    gemm2_shared<<<dim3(DIMSZ / 64, TTOK / 64), 256, 0, stream>>>(Hs, W2sb, out);
    gemm2_routed<<<dim3(DIMSZ / 64, TTOK / 64, NROUT), 256, 0, stream>>>(
        Hc, W2all, counts, tokidx, out);
}

// Round 5
// 238.481 us; speedup vs baseline: 2.2317x; 1.3159x over previous
//
#include <hip/hip_runtime.h>
#include <stdint.h>

typedef unsigned short u16;
typedef __bf16 bf16x8 __attribute__((ext_vector_type(8)));
typedef float f32x4 __attribute__((ext_vector_type(4)));

#define TTOK 2048
#define DIMSZ 1024
#define NROUT 16
#define INTERSZ 512

__device__ __forceinline__ u16 f2bf(float f) {
    unsigned int u = __builtin_bit_cast(unsigned int, f);
    unsigned int r = u + 0x7FFFu + ((u >> 16) & 1u);
    return (u16)(r >> 16);
}

__device__ __forceinline__ void gl2lds16(const void* g, void* l) {
    __builtin_amdgcn_global_load_lds(
        (const __attribute__((address_space(1))) void*)(uintptr_t)g,
        (__attribute__((address_space(3))) void*)(uintptr_t)l,
        16, 0, 0);
}

// ---- one-dispatch fp32->bf16 cast of (w1|sw1), (w3|sw3), (w2|sw2) ----
#define NA4 (NROUT * INTERSZ * DIMSZ / 4)   // 2,097,152 float4 per routed tensor
#define NB4 (DIMSZ * DIMSZ / 4)             //   262,144 float4 per shared tensor
#define NR4 (NA4 + NB4)                     // 2,359,296 per group
__global__ void cast_all(const float* __restrict__ w1, const float* __restrict__ sw1,
                         const float* __restrict__ w3, const float* __restrict__ sw3,
                         const float* __restrict__ w2, const float* __restrict__ sw2,
                         u16* __restrict__ W1b, u16* __restrict__ W3b,
                         u16* __restrict__ W2b) {
    const int n4 = 3 * NR4;
    for (int i = blockIdx.x * blockDim.x + threadIdx.x; i < n4;
         i += gridDim.x * blockDim.x) {
        int r = i / NR4;            // 0,1,2 (const-div)
        int j = i - r * NR4;
        const float* a; const float* b; u16* d;
        if (r == 0)      { a = w1; b = sw1; d = W1b; }
        else if (r == 1) { a = w3; b = sw3; d = W3b; }
        else             { a = w2; b = sw2; d = W2b; }
        float4 v = (j < NA4) ? ((const float4*)a)[j] : ((const float4*)b)[j - NA4];
        ushort4 o;
        o.x = f2bf(v.x); o.y = f2bf(v.y); o.z = f2bf(v.z); o.w = f2bf(v.w);
        *(ushort4*)&d[(size_t)j * 4] = o;
    }
}

// ---- gate scores v2: one block per token, 4 waves split the 1024-dim dot ----
// lane loads 1 float4 of x and 16 float4 of gw; wave shuffle-reduce; LDS combine;
// lane 0 serial top-2 (strict >, first-index tie-break = jax top_k semantics).
__global__ __launch_bounds__(256) void gate_score(
    const float* __restrict__ x, const float* __restrict__ gw,
    int* __restrict__ topi, float2* __restrict__ topw, u16* __restrict__ Xbf) {
    const int t = blockIdx.x;
    const int tid = threadIdx.x;
    const int wave = tid >> 6, lane = tid & 63;
    const int d0 = tid * 4;                       // 256 threads * 4 dims = 1024
    float4 xv = *(const float4*)(x + (size_t)t * DIMSZ + d0);
    ushort4 o;
    o.x = f2bf(xv.x); o.y = f2bf(xv.y); o.z = f2bf(xv.z); o.w = f2bf(xv.w);
    *(ushort4*)&Xbf[(size_t)t * DIMSZ + d0] = o;

    float acc[16];
    #pragma unroll
    for (int e = 0; e < 16; ++e) {
        float4 g = *(const float4*)(gw + e * DIMSZ + d0);
        acc[e] = xv.x * g.x + xv.y * g.y + xv.z * g.z + xv.w * g.w;
    }
    #pragma unroll
    for (int off = 32; off > 0; off >>= 1) {
        #pragma unroll
        for (int e = 0; e < 16; ++e) acc[e] += __shfl_xor(acc[e], off);
    }
    __shared__ float part[4][16];
    __shared__ float sfin[16];
    if (lane < 16) part[wave][lane] = acc[lane];
    __syncthreads();
    if (wave == 0 && lane < 16) {
        float s = part[0][lane] + part[1][lane] + part[2][lane] + part[3][lane];
        sfin[lane] = 1.f / (1.f + expf(-s));
    }
    __syncthreads();
    if (tid == 0) {
        int i0 = 0; float v0 = sfin[0];
        #pragma unroll
        for (int e = 1; e < 16; ++e) { float v = sfin[e]; if (v > v0) { v0 = v; i0 = e; } }
        int i1 = -1; float v1 = -1e30f;
        #pragma unroll
        for (int e = 0; e < 16; ++e) { float v = sfin[e]; if (e != i0 && v > v1) { v1 = v; i1 = e; } }
        float inv = 1.f / (v0 + v1);
        topi[t] = i0 | (i1 << 8);
        topw[t] = make_float2(v0 * inv, v1 * inv);
    }
}

// ---- route: one block per expert; block-wide prefix sum -> ordered compact lists ----
__global__ __launch_bounds__(256) void route_kernel(
    const int* __restrict__ topi, const float2* __restrict__ topw,
    int* __restrict__ counts, int* __restrict__ tokidx, float* __restrict__ tokw) {
    const int e = blockIdx.x;
    const int tid = threadIdx.x;
    int p[8]; int m[8]; int cnt = 0;
    #pragma unroll
    for (int j = 0; j < 8; ++j) {
        int t = tid * 8 + j;
        p[j] = topi[t];
        m[j] = ((p[j] & 255) == e) || ((p[j] >> 8) == e) ? 1 : 0;
        cnt += m[j];
    }
    const int lane = tid & 63, wave = tid >> 6;
    int v = cnt;
    #pragma unroll
    for (int off = 1; off < 64; off <<= 1) {
        int u = __shfl_up(v, off);
        if (lane >= off) v += u;
    }
    __shared__ int wsum[4];
    if (lane == 63) wsum[wave] = v;
    __syncthreads();
    int wbase = 0;
    #pragma unroll
    for (int w = 0; w < 4; ++w) wbase += (w < wave) ? wsum[w] : 0;
    int base = wbase + v - cnt;  // exclusive prefix
    #pragma unroll
    for (int j = 0; j < 8; ++j) {
        if (m[j]) {
            int t = tid * 8 + j;
            float2 w2 = topw[t];
            tokidx[e * TTOK + base] = t;
            tokw[e * TTOK + base] = ((p[j] & 255) == e) ? w2.x : w2.y;
            ++base;
        }
    }
    if (tid == 0) counts[e] = wsum[0] + wsum[1] + wsum[2] + wsum[3];
}

// ---- GEMM1 sparse: BM=64 BN=64 BK=64, 4 waves (2x2, 32x32 wave tile) ----
// e<16: routed (gathered rows), e>=16: shared chunk (all tokens, weight 1)
__global__ __launch_bounds__(256) void gemm1s(
    const u16* __restrict__ Xbf, const u16* __restrict__ W1b,
    const u16* __restrict__ W3b, const int* __restrict__ counts,
    const int* __restrict__ tokidx, const float* __restrict__ tokw,
    u16* __restrict__ Hc, u16* __restrict__ Hs) {
    const int e = blockIdx.z;
    const int cnt = (e < NROUT) ? counts[e] : TTOK;
    const int m0 = blockIdx.y * 64;
    if (m0 >= cnt) return;
    const int n0 = blockIdx.x * 64;
    __shared__ u16 As[64 * 64], B1s[64 * 64], B3s[64 * 64];
    const size_t eoff = (size_t)e * INTERSZ * DIMSZ;
    const u16* B1 = W1b + eoff + (size_t)n0 * DIMSZ;
    const u16* B3 = W3b + eoff + (size_t)n0 * DIMSZ;
    const int tid = threadIdx.x;

    int rowi[2], cgsi[2]; size_t arow[2];
    #pragma unroll
    for (int i = 0; i < 2; ++i) {
        int c = tid + i * 256;
        rowi[i] = c >> 3;
        cgsi[i] = ((c & 7) ^ (rowi[i] & 7)) * 8;
        int slot = m0 + rowi[i];
        int g;
        if (e < NROUT) g = (slot < cnt) ? tokidx[e * TTOK + slot] : 0;
        else           g = slot;
        arow[i] = (size_t)g * DIMSZ;
    }
    f32x4 acc1[2][2] = {}; f32x4 acc3[2][2] = {};
    const int wave = tid >> 6, lane = tid & 63;
    const int wm = (wave >> 1) * 32, wn = (wave & 1) * 32;
    const int lr = lane & 15, lq = lane >> 4;

    for (int kt = 0; kt < DIMSZ / 64; ++kt) {
        const int k0 = kt * 64;
        #pragma unroll
        for (int i = 0; i < 2; ++i) {
            int c = tid + i * 256;
            int boff = rowi[i] * DIMSZ + k0 + cgsi[i];
            gl2lds16(Xbf + arow[i] + k0 + cgsi[i], &As[c * 8]);
            gl2lds16(B1 + boff, &B1s[c * 8]);
            gl2lds16(B3 + boff, &B3s[c * 8]);
        }
        __syncthreads();
        #pragma unroll
        for (int ks = 0; ks < 2; ++ks) {
            bf16x8 af[2], b1f[2], b3f[2];
            const int g = lq + ks * 4;
            #pragma unroll
            for (int mt = 0; mt < 2; ++mt) {
                int m = wm + mt * 16 + lr;
                af[mt] = *(const bf16x8*)&As[(m * 8 + (g ^ (m & 7))) * 8];
            }
            #pragma unroll
            for (int nt = 0; nt < 2; ++nt) {
                int n = wn + nt * 16 + lr;
                int ch = (n * 8 + (g ^ (n & 7))) * 8;
                b1f[nt] = *(const bf16x8*)&B1s[ch];
                b3f[nt] = *(const bf16x8*)&B3s[ch];
            }
            #pragma unroll
            for (int mt = 0; mt < 2; ++mt) {
                #pragma unroll
                for (int nt = 0; nt < 2; ++nt) {
                    acc1[mt][nt] = __builtin_amdgcn_mfma_f32_16x16x32_bf16(af[mt], b1f[nt], acc1[mt][nt], 0, 0, 0);
                    acc3[mt][nt] = __builtin_amdgcn_mfma_f32_16x16x32_bf16(af[mt], b3f[nt], acc3[mt][nt], 0, 0, 0);
                }
            }
        }
        __syncthreads();
    }
    #pragma unroll
    for (int mt = 0; mt < 2; ++mt) {
        #pragma unroll
        for (int nt = 0; nt < 2; ++nt) {
            #pragma unroll
            for (int r = 0; r < 4; ++r) {
                int m = wm + mt * 16 + lq * 4 + r;
                int n = wn + nt * 16 + lr;
                int slot = m0 + m;
                bool valid = slot < cnt;
                float h1 = acc1[mt][nt][r], h3 = acc3[mt][nt][r];
                float hv = 0.f;
                if (valid) {
                    float tw = (e < NROUT) ? tokw[e * TTOK + slot] : 1.0f;
                    hv = h1 / (1.f + __expf(-h1)) * h3 * tw;
                }
                if (e < NROUT)
                    Hc[((size_t)e * TTOK + slot) * INTERSZ + n0 + n] = f2bf(hv);
                else
                    Hs[(size_t)slot * DIMSZ + (e - NROUT) * INTERSZ + n0 + n] = f2bf(hv);
            }
        }
    }
}

// ---- GEMM2 shared: out[t,d] = Hs[t,:] . W2sb[d,:]; BM=64 BN=64, plain store ----
__global__ __launch_bounds__(256) void gemm2_shared(
    const u16* __restrict__ Hs, const u16* __restrict__ W2sb,
    float* __restrict__ out) {
    __shared__ u16 As[64 * 64], Bs[64 * 64];
    const int m0 = blockIdx.y * 64, n0 = blockIdx.x * 64;
    const u16* A0 = Hs + (size_t)m0 * DIMSZ;
    const u16* B0 = W2sb + (size_t)n0 * DIMSZ;
    const int tid = threadIdx.x;
    const int wave = tid >> 6, lane = tid & 63;
    const int wm = (wave >> 1) * 32, wn = (wave & 1) * 32;
    const int lr = lane & 15, lq = lane >> 4;

    f32x4 acc[2][2] = {};
    for (int kt = 0; kt < DIMSZ / 64; ++kt) {
        const int k0 = kt * 64;
        #pragma unroll
        for (int i = 0; i < 2; ++i) {
            int c = tid + i * 256;
            int row = c >> 3;
            int cgs = ((c & 7) ^ (row & 7)) * 8;
            gl2lds16(A0 + (size_t)row * DIMSZ + k0 + cgs, &As[c * 8]);
            gl2lds16(B0 + (size_t)row * DIMSZ + k0 + cgs, &Bs[c * 8]);
        }
        __syncthreads();
        #pragma unroll
        for (int ks = 0; ks < 2; ++ks) {
            bf16x8 af[2], bfr[2];
            const int g = lq + ks * 4;
            #pragma unroll
            for (int mt = 0; mt < 2; ++mt) {
                int m = wm + mt * 16 + lr;
                af[mt] = *(const bf16x8*)&As[(m * 8 + (g ^ (m & 7))) * 8];
            }
            #pragma unroll
            for (int nt = 0; nt < 2; ++nt) {
                int n = wn + nt * 16 + lr;
                bfr[nt] = *(const bf16x8*)&Bs[(n * 8 + (g ^ (n & 7))) * 8];
            }
            #pragma unroll
            for (int mt = 0; mt < 2; ++mt) {
                #pragma unroll
                for (int nt = 0; nt < 2; ++nt) {
                    acc[mt][nt] = __builtin_amdgcn_mfma_f32_16x16x32_bf16(af[mt], bfr[nt], acc[mt][nt], 0, 0, 0);
                }
            }
        }
        __syncthreads();
    }
    #pragma unroll
    for (int mt = 0; mt < 2; ++mt) {
        #pragma unroll
        for (int nt = 0; nt < 2; ++nt) {
            #pragma unroll
            for (int r = 0; r < 4; ++r) {
                int m = wm + mt * 16 + lq * 4 + r;
                int n = wn + nt * 16 + lr;
                out[(size_t)(m0 + m) * DIMSZ + n0 + n] = acc[mt][nt][r];
            }
        }
    }
}

// ---- GEMM2 routed: BM=64 BN=64, compacted Hc rows @ w2[e]^T, scatter-atomicAdd ----
__global__ __launch_bounds__(256) void gemm2_routed(
    const u16* __restrict__ Hc, const u16* __restrict__ W2b,
    const int* __restrict__ counts, const int* __restrict__ tokidx,
    float* __restrict__ out) {
    const int e = blockIdx.z;
    const int cnt = counts[e];
    const int m0 = blockIdx.y * 64;
    if (m0 >= cnt) return;
    const int n0 = blockIdx.x * 64;
    __shared__ u16 As[64 * 64], Bs[64 * 64];
    const u16* A0 = Hc + ((size_t)e * TTOK + m0) * INTERSZ;
    const u16* B0 = W2b + ((size_t)e * DIMSZ + n0) * INTERSZ;
    const int tid = threadIdx.x;
    const int wave = tid >> 6, lane = tid & 63;
    const int wm = (wave >> 1) * 32, wn = (wave & 1) * 32;
    const int lr = lane & 15, lq = lane >> 4;

    f32x4 acc[2][2] = {};
    for (int kt = 0; kt < INTERSZ / 64; ++kt) {
        const int k0 = kt * 64;
        #pragma unroll
        for (int i = 0; i < 2; ++i) {
            int c = tid + i * 256;
            int row = c >> 3;
            int cgs = ((c & 7) ^ (row & 7)) * 8;
            gl2lds16(A0 + (size_t)row * INTERSZ + k0 + cgs, &As[c * 8]);
            gl2lds16(B0 + (size_t)row * INTERSZ + k0 + cgs, &Bs[c * 8]);
        }
        __syncthreads();
        #pragma unroll
        for (int ks = 0; ks < 2; ++ks) {
            bf16x8 af[2], bfr[2];
            const int g = lq + ks * 4;
            #pragma unroll
            for (int mt = 0; mt < 2; ++mt) {
                int m = wm + mt * 16 + lr;
                af[mt] = *(const bf16x8*)&As[(m * 8 + (g ^ (m & 7))) * 8];
            }
            #pragma unroll
            for (int nt = 0; nt < 2; ++nt) {
                int n = wn + nt * 16 + lr;
                bfr[nt] = *(const bf16x8*)&Bs[(n * 8 + (g ^ (n & 7))) * 8];
            }
            #pragma unroll
            for (int mt = 0; mt < 2; ++mt) {
                #pragma unroll
                for (int nt = 0; nt < 2; ++nt) {
                    acc[mt][nt] = __builtin_amdgcn_mfma_f32_16x16x32_bf16(af[mt], bfr[nt], acc[mt][nt], 0, 0, 0);
                }
            }
        }
        __syncthreads();
    }
    #pragma unroll
    for (int mt = 0; mt < 2; ++mt) {
        #pragma unroll
        for (int r = 0; r < 4; ++r) {
            int m = wm + mt * 16 + lq * 4 + r;
            int slot = m0 + m;
            if (slot < cnt) {
                int t = tokidx[e * TTOK + slot];
                #pragma unroll
                for (int nt = 0; nt < 2; ++nt) {
                    int n = wn + nt * 16 + lr;
                    unsafeAtomicAdd(&out[(size_t)t * DIMSZ + n0 + n], acc[mt][nt][r]);
                }
            }
        }
    }
}

extern "C" void kernel_launch(void* const* d_in, const int* in_sizes, int n_in,
                              void* d_out, int out_size, void* d_ws, size_t ws_size,
                              hipStream_t stream) {
    const float* x      = (const float*)d_in[0];
    const float* gate_w = (const float*)d_in[1];
    const float* w1     = (const float*)d_in[2];
    const float* w2     = (const float*)d_in[3];
    const float* w3     = (const float*)d_in[4];
    const float* sw1    = (const float*)d_in[5];
    const float* sw2    = (const float*)d_in[6];
    const float* sw3    = (const float*)d_in[7];
    float* out = (float*)d_out;

    char* ws = (char*)d_ws;
    const size_t SZ_W   = (size_t)(NROUT + 2) * INTERSZ * DIMSZ * 2;  // 18,874,368 B each
    const size_t SZ_XBF = (size_t)TTOK * DIMSZ * 2;
    u16*   W1b    = (u16*)(ws);
    u16*   W3b    = (u16*)(ws + SZ_W);
    u16*   W2all  = (u16*)(ws + 2 * SZ_W);                 // [16][1024][512] ++ [1024][1024]
    u16*   Xbf    = (u16*)(ws + 3 * SZ_W);
    char*  route  = ws + 3 * SZ_W + SZ_XBF;
    int*   counts = (int*)route;                           // 16 ints
    int*   topi   = (int*)(route + 256);                   // [2048]
    float2* topw  = (float2*)(route + 256 + TTOK * 4);     // [2048]
    int*   tokidx = (int*)(route + 256 + TTOK * 12);       // [16][2048]
    float* tokw   = (float*)(route + 256 + TTOK * 12 + 16 * TTOK * 4); // [16][2048]
    char*  hbuf   = route + 256 + TTOK * 12 + 2 * (size_t)16 * TTOK * 4;
    u16*   Hc     = (u16*)hbuf;                            // [16][2048][512] bf16
    u16*   Hs     = (u16*)(hbuf + (size_t)NROUT * TTOK * INTERSZ * 2); // [2048][1024]
    u16*   W2sb   = W2all + (size_t)NROUT * DIMSZ * INTERSZ;

    cast_all<<<8192, 256, 0, stream>>>(w1, sw1, w3, sw3, w2, sw2, W1b, W3b, W2all);
    gate_score<<<TTOK, 256, 0, stream>>>(x, gate_w, topi, topw, Xbf);
    route_kernel<<<NROUT, 256, 0, stream>>>(topi, topw, counts, tokidx, tokw);
    gemm1s<<<dim3(INTERSZ / 64, TTOK / 64, NROUT + 2), 256, 0, stream>>>(
        Xbf, W1b, W3b, counts, tokidx, tokw, Hc, Hs);
    gemm2_shared<<<dim3(DIMSZ / 64, TTOK / 64), 256, 0, stream>>>(Hs, W2sb, out);
    gemm2_routed<<<dim3(DIMSZ / 64, TTOK / 64, NROUT), 256, 0, stream>>>(
        Hc, W2all, counts, tokidx, out);
}

// Round 7
// 237.036 us; speedup vs baseline: 2.2453x; 1.0061x over previous
//
#include <hip/hip_runtime.h>
#include <stdint.h>

typedef unsigned short u16;
typedef __bf16 bf16x8 __attribute__((ext_vector_type(8)));
typedef float f32x4 __attribute__((ext_vector_type(4)));
typedef unsigned short u16x8 __attribute__((ext_vector_type(8)));

#define TTOK 2048
#define DIMSZ 1024
#define NROUT 16
#define INTERSZ 512

__device__ __forceinline__ u16 f2bf(float f) {
    unsigned int u = __builtin_bit_cast(unsigned int, f);
    unsigned int r = u + 0x7FFFu + ((u >> 16) & 1u);
    return (u16)(r >> 16);
}

__device__ __forceinline__ void gl2lds16(const void* g, void* l) {
    __builtin_amdgcn_global_load_lds(
        (const __attribute__((address_space(1))) void*)(uintptr_t)g,
        (__attribute__((address_space(3))) void*)(uintptr_t)l,
        16, 0, 0);
}

// ---- fp32->bf16 cast: grid.y selects group (w1|sw1),(w3|sw3),(w2|sw2) ----
#define NA4 (NROUT * INTERSZ * DIMSZ / 4)
#define NB4 (DIMSZ * DIMSZ / 4)
#define NA8 (NA4 / 2)
#define NR8 ((NA4 + NB4) / 2)
__global__ void cast_all(const float* __restrict__ w1, const float* __restrict__ sw1,
                         const float* __restrict__ w3, const float* __restrict__ sw3,
                         const float* __restrict__ w2, const float* __restrict__ sw2,
                         u16* __restrict__ W1b, u16* __restrict__ W3b,
                         u16* __restrict__ W2b) {
    const int r = blockIdx.y;
    const float* a; const float* b; u16* d;
    if (r == 0)      { a = w1; b = sw1; d = W1b; }
    else if (r == 1) { a = w3; b = sw3; d = W3b; }
    else             { a = w2; b = sw2; d = W2b; }
    for (int j = blockIdx.x * blockDim.x + threadIdx.x; j < NR8;
         j += gridDim.x * blockDim.x) {
        const float4* src = (j < NA8) ? (const float4*)a + 2 * (size_t)j
                                      : (const float4*)b + 2 * (size_t)(j - NA8);
        float4 v0 = src[0], v1 = src[1];
        u16x8 o;
        o[0] = f2bf(v0.x); o[1] = f2bf(v0.y); o[2] = f2bf(v0.z); o[3] = f2bf(v0.w);
        o[4] = f2bf(v1.x); o[5] = f2bf(v1.y); o[6] = f2bf(v1.z); o[7] = f2bf(v1.w);
        *(u16x8*)&d[(size_t)j * 8] = o;
    }
}

// ---- gate scores: one block per token, 4 waves split the 1024-dim dot ----
__global__ __launch_bounds__(256) void gate_score(
    const float* __restrict__ x, const float* __restrict__ gw,
    int* __restrict__ topi, float2* __restrict__ topw, u16* __restrict__ Xbf) {
    const int t = blockIdx.x;
    const int tid = threadIdx.x;
    const int wave = tid >> 6, lane = tid & 63;
    const int d0 = tid * 4;
    float4 xv = *(const float4*)(x + (size_t)t * DIMSZ + d0);
    ushort4 o;
    o.x = f2bf(xv.x); o.y = f2bf(xv.y); o.z = f2bf(xv.z); o.w = f2bf(xv.w);
    *(ushort4*)&Xbf[(size_t)t * DIMSZ + d0] = o;

    float acc[16];
    #pragma unroll
    for (int e = 0; e < 16; ++e) {
        float4 g = *(const float4*)(gw + e * DIMSZ + d0);
        acc[e] = xv.x * g.x + xv.y * g.y + xv.z * g.z + xv.w * g.w;
    }
    #pragma unroll
    for (int off = 32; off > 0; off >>= 1) {
        #pragma unroll
        for (int e = 0; e < 16; ++e) acc[e] += __shfl_xor(acc[e], off);
    }
    __shared__ float part[4][16];
    __shared__ float sfin[16];
    if (lane < 16) part[wave][lane] = acc[lane];
    __syncthreads();
    if (wave == 0 && lane < 16) {
        float s = part[0][lane] + part[1][lane] + part[2][lane] + part[3][lane];
        sfin[lane] = 1.f / (1.f + expf(-s));
    }
    __syncthreads();
    if (tid == 0) {
        int i0 = 0; float v0 = sfin[0];
        #pragma unroll
        for (int e = 1; e < 16; ++e) { float v = sfin[e]; if (v > v0) { v0 = v; i0 = e; } }
        int i1 = -1; float v1 = -1e30f;
        #pragma unroll
        for (int e = 0; e < 16; ++e) { float v = sfin[e]; if (e != i0 && v > v1) { v1 = v; i1 = e; } }
        float inv = 1.f / (v0 + v1);
        topi[t] = i0 | (i1 << 8);
        topw[t] = make_float2(v0 * inv, v1 * inv);
    }
}

// ---- route: one block per expert; block-wide prefix sum -> ordered compact lists ----
__global__ __launch_bounds__(256) void route_kernel(
    const int* __restrict__ topi, const float2* __restrict__ topw,
    int* __restrict__ counts, int* __restrict__ tokidx, float* __restrict__ tokw) {
    const int e = blockIdx.x;
    const int tid = threadIdx.x;
    int p[8]; int m[8]; int cnt = 0;
    #pragma unroll
    for (int j = 0; j < 8; ++j) {
        int t = tid * 8 + j;
        p[j] = topi[t];
        m[j] = ((p[j] & 255) == e) || ((p[j] >> 8) == e) ? 1 : 0;
        cnt += m[j];
    }
    const int lane = tid & 63, wave = tid >> 6;
    int v = cnt;
    #pragma unroll
    for (int off = 1; off < 64; off <<= 1) {
        int u = __shfl_up(v, off);
        if (lane >= off) v += u;
    }
    __shared__ int wsum[4];
    if (lane == 63) wsum[wave] = v;
    __syncthreads();
    int wbase = 0;
    #pragma unroll
    for (int w = 0; w < 4; ++w) wbase += (w < wave) ? wsum[w] : 0;
    int base = wbase + v - cnt;
    #pragma unroll
    for (int j = 0; j < 8; ++j) {
        if (m[j]) {
            int t = tid * 8 + j;
            float2 w2 = topw[t];
            tokidx[e * TTOK + base] = t;
            tokw[e * TTOK + base] = ((p[j] & 255) == e) ? w2.x : w2.y;
            ++base;
        }
    }
    if (tid == 0) counts[e] = wsum[0] + wsum[1] + wsum[2] + wsum[3];
}

// ---- GEMM1 sparse: BM=64 BN=128 BK=64, 4 waves (2x2), wave tile 32x64 ----
__global__ __launch_bounds__(256) void gemm1s(
    const u16* __restrict__ Xbf, const u16* __restrict__ W1b,
    const u16* __restrict__ W3b, const int* __restrict__ counts,
    const int* __restrict__ tokidx, const float* __restrict__ tokw,
    u16* __restrict__ Hc, u16* __restrict__ Hs) {
    const int e = blockIdx.z;
    const int cnt = (e < NROUT) ? counts[e] : TTOK;
    const int m0 = blockIdx.y * 64;
    if (m0 >= cnt) return;
    const int n0 = blockIdx.x * 128;
    __shared__ u16 As[64 * 64], B1s[128 * 64], B3s[128 * 64];
    const size_t eoff = (size_t)e * INTERSZ * DIMSZ;
    const u16* B1 = W1b + eoff + (size_t)n0 * DIMSZ;
    const u16* B3 = W3b + eoff + (size_t)n0 * DIMSZ;
    const int tid = threadIdx.x;

    int rowa[2], cgsa[2]; size_t arow[2];
    #pragma unroll
    for (int i = 0; i < 2; ++i) {
        int c = tid + i * 256;
        rowa[i] = c >> 3;
        cgsa[i] = ((c & 7) ^ (rowa[i] & 7)) * 8;
        int slot = m0 + rowa[i];
        int g;
        if (e < NROUT) g = (slot < cnt) ? tokidx[e * TTOK + slot] : 0;
        else           g = slot;
        arow[i] = (size_t)g * DIMSZ;
    }
    int rowb[4], cgsb[4];
    #pragma unroll
    for (int i = 0; i < 4; ++i) {
        int c = tid + i * 256;
        rowb[i] = c >> 3;
        cgsb[i] = ((c & 7) ^ (rowb[i] & 7)) * 8;
    }
    f32x4 acc1[2][4] = {}; f32x4 acc3[2][4] = {};
    const int wave = tid >> 6, lane = tid & 63;
    const int wm = (wave >> 1) * 32, wn = (wave & 1) * 64;
    const int lr = lane & 15, lq = lane >> 4;

    for (int kt = 0; kt < DIMSZ / 64; ++kt) {
        const int k0 = kt * 64;
        #pragma unroll
        for (int i = 0; i < 2; ++i) {
            int c = tid + i * 256;
            gl2lds16(Xbf + arow[i] + k0 + cgsa[i], &As[c * 8]);
        }
        #pragma unroll
        for (int i = 0; i < 4; ++i) {
            int c = tid + i * 256;
            int boff = rowb[i] * DIMSZ + k0 + cgsb[i];
            gl2lds16(B1 + boff, &B1s[c * 8]);
            gl2lds16(B3 + boff, &B3s[c * 8]);
        }
        __syncthreads();
        #pragma unroll
        for (int ks = 0; ks < 2; ++ks) {
            bf16x8 af[2], b1f[4], b3f[4];
            const int g = lq + ks * 4;
            #pragma unroll
            for (int mt = 0; mt < 2; ++mt) {
                int m = wm + mt * 16 + lr;
                af[mt] = *(const bf16x8*)&As[(m * 8 + (g ^ (m & 7))) * 8];
            }
            #pragma unroll
            for (int nt = 0; nt < 4; ++nt) {
                int n = wn + nt * 16 + lr;
                int ch = (n * 8 + (g ^ (n & 7))) * 8;
                b1f[nt] = *(const bf16x8*)&B1s[ch];
                b3f[nt] = *(const bf16x8*)&B3s[ch];
            }
            #pragma unroll
            for (int mt = 0; mt < 2; ++mt) {
                #pragma unroll
                for (int nt = 0; nt < 4; ++nt) {
                    acc1[mt][nt] = __builtin_amdgcn_mfma_f32_16x16x32_bf16(af[mt], b1f[nt], acc1[mt][nt], 0, 0, 0);
                    acc3[mt][nt] = __builtin_amdgcn_mfma_f32_16x16x32_bf16(af[mt], b3f[nt], acc3[mt][nt], 0, 0, 0);
                }
            }
        }
        __syncthreads();
    }
    #pragma unroll
    for (int mt = 0; mt < 2; ++mt) {
        #pragma unroll
        for (int nt = 0; nt < 4; ++nt) {
            #pragma unroll
            for (int r = 0; r < 4; ++r) {
                int m = wm + mt * 16 + lq * 4 + r;
                int n = wn + nt * 16 + lr;
                int slot = m0 + m;
                bool valid = slot < cnt;
                float h1 = acc1[mt][nt][r], h3 = acc3[mt][nt][r];
                float hv = 0.f;
                if (valid) {
                    float tw = (e < NROUT) ? tokw[e * TTOK + slot] : 1.0f;
                    hv = h1 / (1.f + __expf(-h1)) * h3 * tw;
                }
                if (e < NROUT)
                    Hc[((size_t)e * TTOK + slot) * INTERSZ + n0 + n] = f2bf(hv);
                else
                    Hs[(size_t)slot * DIMSZ + (e - NROUT) * INTERSZ + n0 + n] = f2bf(hv);
            }
        }
    }
}

// ---- GEMM2 unified, race-free: out zero-initialized, ALL blocks atomicAdd ----
// z<16 routed (K=512, gathered token scatter), z==16 shared (K=1024, identity rows)
__global__ __launch_bounds__(256) void gemm2u(
    const u16* __restrict__ Hc, const u16* __restrict__ Hs,
    const u16* __restrict__ W2b, const u16* __restrict__ W2sb,
    const int* __restrict__ counts, const int* __restrict__ tokidx,
    float* __restrict__ out) {
    const int e = blockIdx.z;
    const bool routed = (e < NROUT);
    const int cnt = routed ? counts[e] : TTOK;
    const int m0 = blockIdx.y * 64;
    if (m0 >= cnt) return;
    const int n0 = blockIdx.x * 64;
    const int klen = routed ? INTERSZ : DIMSZ;
    __shared__ u16 As[64 * 64], Bs[64 * 64];
    const u16* A0 = routed ? Hc + ((size_t)e * TTOK + m0) * INTERSZ
                           : Hs + (size_t)m0 * DIMSZ;
    const u16* B0 = routed ? W2b + ((size_t)e * DIMSZ + n0) * INTERSZ
                           : W2sb + (size_t)n0 * DIMSZ;
    const int tid = threadIdx.x;
    const int wave = tid >> 6, lane = tid & 63;
    const int wm = (wave >> 1) * 32, wn = (wave & 1) * 32;
    const int lr = lane & 15, lq = lane >> 4;

    int rowi[2], cgsi[2];
    #pragma unroll
    for (int i = 0; i < 2; ++i) {
        int c = tid + i * 256;
        rowi[i] = c >> 3;
        cgsi[i] = ((c & 7) ^ (rowi[i] & 7)) * 8;
    }

    f32x4 acc[2][2] = {};
    for (int kt = 0; kt < klen / 64; ++kt) {
        const int k0 = kt * 64;
        #pragma unroll
        for (int i = 0; i < 2; ++i) {
            int c = tid + i * 256;
            gl2lds16(A0 + (size_t)rowi[i] * klen + k0 + cgsi[i], &As[c * 8]);
            gl2lds16(B0 + (size_t)rowi[i] * klen + k0 + cgsi[i], &Bs[c * 8]);
        }
        __syncthreads();
        #pragma unroll
        for (int ks = 0; ks < 2; ++ks) {
            bf16x8 af[2], bfr[2];
            const int g = lq + ks * 4;
            #pragma unroll
            for (int mt = 0; mt < 2; ++mt) {
                int m = wm + mt * 16 + lr;
                af[mt] = *(const bf16x8*)&As[(m * 8 + (g ^ (m & 7))) * 8];
            }
            #pragma unroll
            for (int nt = 0; nt < 2; ++nt) {
                int n = wn + nt * 16 + lr;
                bfr[nt] = *(const bf16x8*)&Bs[(n * 8 + (g ^ (n & 7))) * 8];
            }
            #pragma unroll
            for (int mt = 0; mt < 2; ++mt) {
                #pragma unroll
                for (int nt = 0; nt < 2; ++nt) {
                    acc[mt][nt] = __builtin_amdgcn_mfma_f32_16x16x32_bf16(af[mt], bfr[nt], acc[mt][nt], 0, 0, 0);
                }
            }
        }
        __syncthreads();
    }
    #pragma unroll
    for (int mt = 0; mt < 2; ++mt) {
        #pragma unroll
        for (int r = 0; r < 4; ++r) {
            int m = wm + mt * 16 + lq * 4 + r;
            int slot = m0 + m;
            if (slot < cnt) {
                int t = routed ? tokidx[e * TTOK + slot] : slot;
                #pragma unroll
                for (int nt = 0; nt < 2; ++nt) {
                    int n = wn + nt * 16 + lr;
                    unsafeAtomicAdd(&out[(size_t)t * DIMSZ + n0 + n], acc[mt][nt][r]);
                }
            }
        }
    }
}

extern "C" void kernel_launch(void* const* d_in, const int* in_sizes, int n_in,
                              void* d_out, int out_size, void* d_ws, size_t ws_size,
                              hipStream_t stream) {
    const float* x      = (const float*)d_in[0];
    const float* gate_w = (const float*)d_in[1];
    const float* w1     = (const float*)d_in[2];
    const float* w2     = (const float*)d_in[3];
    const float* w3     = (const float*)d_in[4];
    const float* sw1    = (const float*)d_in[5];
    const float* sw2    = (const float*)d_in[6];
    const float* sw3    = (const float*)d_in[7];
    float* out = (float*)d_out;

    char* ws = (char*)d_ws;
    const size_t SZ_W   = (size_t)(NROUT + 2) * INTERSZ * DIMSZ * 2;
    const size_t SZ_XBF = (size_t)TTOK * DIMSZ * 2;
    u16*   W1b    = (u16*)(ws);
    u16*   W3b    = (u16*)(ws + SZ_W);
    u16*   W2all  = (u16*)(ws + 2 * SZ_W);
    u16*   Xbf    = (u16*)(ws + 3 * SZ_W);
    char*  route  = ws + 3 * SZ_W + SZ_XBF;
    int*   counts = (int*)route;
    int*   topi   = (int*)(route + 256);
    float2* topw  = (float2*)(route + 256 + TTOK * 4);
    int*   tokidx = (int*)(route + 256 + TTOK * 12);
    float* tokw   = (float*)(route + 256 + TTOK * 12 + 16 * TTOK * 4);
    char*  hbuf   = route + 256 + TTOK * 12 + 2 * (size_t)16 * TTOK * 4;
    u16*   Hc     = (u16*)hbuf;                                        // [16][2048][512]
    u16*   Hs     = (u16*)(hbuf + (size_t)NROUT * TTOK * INTERSZ * 2); // [2048][1024]
    u16*   W2sb   = W2all + (size_t)NROUT * DIMSZ * INTERSZ;

    hipMemsetAsync(out, 0, (size_t)TTOK * DIMSZ * 4, stream);
    cast_all<<<dim3(2048, 3), 256, 0, stream>>>(w1, sw1, w3, sw3, w2, sw2, W1b, W3b, W2all);
    gate_score<<<TTOK, 256, 0, stream>>>(x, gate_w, topi, topw, Xbf);
    route_kernel<<<NROUT, 256, 0, stream>>>(topi, topw, counts, tokidx, tokw);
    gemm1s<<<dim3(INTERSZ / 128, TTOK / 64, NROUT + 2), 256, 0, stream>>>(
        Xbf, W1b, W3b, counts, tokidx, tokw, Hc, Hs);
    gemm2u<<<dim3(DIMSZ / 64, TTOK / 64, NROUT + 1), 256, 0, stream>>>(
        Hc, Hs, W2all, W2sb, counts, tokidx, out);
}

// Round 8
// 230.819 us; speedup vs baseline: 2.3058x; 1.0269x over previous
//
#include <hip/hip_runtime.h>
#include <stdint.h>

typedef unsigned short u16;
typedef __bf16 bf16x8 __attribute__((ext_vector_type(8)));
typedef float f32x4 __attribute__((ext_vector_type(4)));
typedef unsigned short u16x8 __attribute__((ext_vector_type(8)));

#define TTOK 2048
#define DIMSZ 1024
#define NROUT 16
#define INTERSZ 512

__device__ __forceinline__ u16 f2bf(float f) {
    unsigned int u = __builtin_bit_cast(unsigned int, f);
    unsigned int r = u + 0x7FFFu + ((u >> 16) & 1u);
    return (u16)(r >> 16);
}

__device__ __forceinline__ void gl2lds16(const void* g, void* l) {
    __builtin_amdgcn_global_load_lds(
        (const __attribute__((address_space(1))) void*)(uintptr_t)g,
        (__attribute__((address_space(3))) void*)(uintptr_t)l,
        16, 0, 0);
}

// ---- prep: grid.y<3 = weight cast groups; grid.y==3 = gate + Xbf + zero(out) ----
#define NA4 (NROUT * INTERSZ * DIMSZ / 4)
#define NB4 (DIMSZ * DIMSZ / 4)
#define NA8 (NA4 / 2)
#define NR8 ((NA4 + NB4) / 2)
__global__ __launch_bounds__(256) void prep(
    const float* __restrict__ w1, const float* __restrict__ sw1,
    const float* __restrict__ w3, const float* __restrict__ sw3,
    const float* __restrict__ w2, const float* __restrict__ sw2,
    u16* __restrict__ W1b, u16* __restrict__ W3b, u16* __restrict__ W2b,
    const float* __restrict__ x, const float* __restrict__ gw,
    int* __restrict__ topi, float2* __restrict__ topw,
    u16* __restrict__ Xbf, float* __restrict__ out) {
    const int r = blockIdx.y;
    const int tid = threadIdx.x;
    if (r < 3) {
        const float* a; const float* b; u16* d;
        if (r == 0)      { a = w1; b = sw1; d = W1b; }
        else if (r == 1) { a = w3; b = sw3; d = W3b; }
        else             { a = w2; b = sw2; d = W2b; }
        const int stride = gridDim.x * blockDim.x;
        for (int j = blockIdx.x * blockDim.x + tid; j < NR8; j += stride) {
            const float4* src = (j < NA8) ? (const float4*)a + 2 * (size_t)j
                                          : (const float4*)b + 2 * (size_t)(j - NA8);
            float4 v0 = src[0], v1 = src[1];
            u16x8 o;
            o[0] = f2bf(v0.x); o[1] = f2bf(v0.y); o[2] = f2bf(v0.z); o[3] = f2bf(v0.w);
            o[4] = f2bf(v1.x); o[5] = f2bf(v1.y); o[6] = f2bf(v1.z); o[7] = f2bf(v1.w);
            *(u16x8*)&d[(size_t)j * 8] = o;
        }
        return;
    }
    // gate branch: one block per token
    const int t = blockIdx.x;
    const int wave = tid >> 6, lane = tid & 63;
    const int d0 = tid * 4;
    // zero the output row (race-free accumulate target for gemm2u)
    *(float4*)(out + (size_t)t * DIMSZ + d0) = make_float4(0.f, 0.f, 0.f, 0.f);
    float4 xv = *(const float4*)(x + (size_t)t * DIMSZ + d0);
    ushort4 o;
    o.x = f2bf(xv.x); o.y = f2bf(xv.y); o.z = f2bf(xv.z); o.w = f2bf(xv.w);
    *(ushort4*)&Xbf[(size_t)t * DIMSZ + d0] = o;

    float acc[16];
    #pragma unroll
    for (int e = 0; e < 16; ++e) {
        float4 g = *(const float4*)(gw + e * DIMSZ + d0);
        acc[e] = xv.x * g.x + xv.y * g.y + xv.z * g.z + xv.w * g.w;
    }
    #pragma unroll
    for (int off = 32; off > 0; off >>= 1) {
        #pragma unroll
        for (int e = 0; e < 16; ++e) acc[e] += __shfl_xor(acc[e], off);
    }
    __shared__ float part[4][16];
    __shared__ float sfin[16];
    if (lane < 16) part[wave][lane] = acc[lane];
    __syncthreads();
    if (wave == 0 && lane < 16) {
        float s = part[0][lane] + part[1][lane] + part[2][lane] + part[3][lane];
        sfin[lane] = 1.f / (1.f + expf(-s));
    }
    __syncthreads();
    if (tid == 0) {
        int i0 = 0; float v0 = sfin[0];
        #pragma unroll
        for (int e = 1; e < 16; ++e) { float v = sfin[e]; if (v > v0) { v0 = v; i0 = e; } }
        int i1 = -1; float v1 = -1e30f;
        #pragma unroll
        for (int e = 0; e < 16; ++e) { float v = sfin[e]; if (e != i0 && v > v1) { v1 = v; i1 = e; } }
        float inv = 1.f / (v0 + v1);
        topi[t] = i0 | (i1 << 8);
        topw[t] = make_float2(v0 * inv, v1 * inv);
    }
}

// ---- route: one block per expert; block-wide prefix sum -> ordered compact lists ----
__global__ __launch_bounds__(256) void route_kernel(
    const int* __restrict__ topi, const float2* __restrict__ topw,
    int* __restrict__ counts, int* __restrict__ tokidx, float* __restrict__ tokw) {
    const int e = blockIdx.x;
    const int tid = threadIdx.x;
    int p[8]; int m[8]; int cnt = 0;
    #pragma unroll
    for (int j = 0; j < 8; ++j) {
        int t = tid * 8 + j;
        p[j] = topi[t];
        m[j] = ((p[j] & 255) == e) || ((p[j] >> 8) == e) ? 1 : 0;
        cnt += m[j];
    }
    const int lane = tid & 63, wave = tid >> 6;
    int v = cnt;
    #pragma unroll
    for (int off = 1; off < 64; off <<= 1) {
        int u = __shfl_up(v, off);
        if (lane >= off) v += u;
    }
    __shared__ int wsum[4];
    if (lane == 63) wsum[wave] = v;
    __syncthreads();
    int wbase = 0;
    #pragma unroll
    for (int w = 0; w < 4; ++w) wbase += (w < wave) ? wsum[w] : 0;
    int base = wbase + v - cnt;
    #pragma unroll
    for (int j = 0; j < 8; ++j) {
        if (m[j]) {
            int t = tid * 8 + j;
            float2 w2 = topw[t];
            tokidx[e * TTOK + base] = t;
            tokw[e * TTOK + base] = ((p[j] & 255) == e) ? w2.x : w2.y;
            ++base;
        }
    }
    if (tid == 0) counts[e] = wsum[0] + wsum[1] + wsum[2] + wsum[3];
}

// ---- GEMM1 sparse: BM=64 BN=128 BK=64, 4 waves (2x2), wave tile 32x64 ----
__global__ __launch_bounds__(256) void gemm1s(
    const u16* __restrict__ Xbf, const u16* __restrict__ W1b,
    const u16* __restrict__ W3b, const int* __restrict__ counts,
    const int* __restrict__ tokidx, const float* __restrict__ tokw,
    u16* __restrict__ Hc, u16* __restrict__ Hs) {
    const int e = blockIdx.z;
    const int cnt = (e < NROUT) ? counts[e] : TTOK;
    const int m0 = blockIdx.y * 64;
    if (m0 >= cnt) return;
    const int n0 = blockIdx.x * 128;
    __shared__ u16 As[64 * 64], B1s[128 * 64], B3s[128 * 64];
    const size_t eoff = (size_t)e * INTERSZ * DIMSZ;
    const u16* B1 = W1b + eoff + (size_t)n0 * DIMSZ;
    const u16* B3 = W3b + eoff + (size_t)n0 * DIMSZ;
    const int tid = threadIdx.x;

    int rowa[2], cgsa[2]; size_t arow[2];
    #pragma unroll
    for (int i = 0; i < 2; ++i) {
        int c = tid + i * 256;
        rowa[i] = c >> 3;
        cgsa[i] = ((c & 7) ^ (rowa[i] & 7)) * 8;
        int slot = m0 + rowa[i];
        int g;
        if (e < NROUT) g = (slot < cnt) ? tokidx[e * TTOK + slot] : 0;
        else           g = slot;
        arow[i] = (size_t)g * DIMSZ;
    }
    int rowb[4], cgsb[4];
    #pragma unroll
    for (int i = 0; i < 4; ++i) {
        int c = tid + i * 256;
        rowb[i] = c >> 3;
        cgsb[i] = ((c & 7) ^ (rowb[i] & 7)) * 8;
    }
    f32x4 acc1[2][4] = {}; f32x4 acc3[2][4] = {};
    const int wave = tid >> 6, lane = tid & 63;
    const int wm = (wave >> 1) * 32, wn = (wave & 1) * 64;
    const int lr = lane & 15, lq = lane >> 4;

    for (int kt = 0; kt < DIMSZ / 64; ++kt) {
        const int k0 = kt * 64;
        #pragma unroll
        for (int i = 0; i < 2; ++i) {
            int c = tid + i * 256;
            gl2lds16(Xbf + arow[i] + k0 + cgsa[i], &As[c * 8]);
        }
        #pragma unroll
        for (int i = 0; i < 4; ++i) {
            int c = tid + i * 256;
            int boff = rowb[i] * DIMSZ + k0 + cgsb[i];
            gl2lds16(B1 + boff, &B1s[c * 8]);
            gl2lds16(B3 + boff, &B3s[c * 8]);
        }
        __syncthreads();
        #pragma unroll
        for (int ks = 0; ks < 2; ++ks) {
            bf16x8 af[2], b1f[4], b3f[4];
            const int g = lq + ks * 4;
            #pragma unroll
            for (int mt = 0; mt < 2; ++mt) {
                int m = wm + mt * 16 + lr;
                af[mt] = *(const bf16x8*)&As[(m * 8 + (g ^ (m & 7))) * 8];
            }
            #pragma unroll
            for (int nt = 0; nt < 4; ++nt) {
                int n = wn + nt * 16 + lr;
                int ch = (n * 8 + (g ^ (n & 7))) * 8;
                b1f[nt] = *(const bf16x8*)&B1s[ch];
                b3f[nt] = *(const bf16x8*)&B3s[ch];
            }
            #pragma unroll
            for (int mt = 0; mt < 2; ++mt) {
                #pragma unroll
                for (int nt = 0; nt < 4; ++nt) {
                    acc1[mt][nt] = __builtin_amdgcn_mfma_f32_16x16x32_bf16(af[mt], b1f[nt], acc1[mt][nt], 0, 0, 0);
                    acc3[mt][nt] = __builtin_amdgcn_mfma_f32_16x16x32_bf16(af[mt], b3f[nt], acc3[mt][nt], 0, 0, 0);
                }
            }
        }
        __syncthreads();
    }
    #pragma unroll
    for (int mt = 0; mt < 2; ++mt) {
        #pragma unroll
        for (int nt = 0; nt < 4; ++nt) {
            #pragma unroll
            for (int r = 0; r < 4; ++r) {
                int m = wm + mt * 16 + lq * 4 + r;
                int n = wn + nt * 16 + lr;
                int slot = m0 + m;
                bool valid = slot < cnt;
                float h1 = acc1[mt][nt][r], h3 = acc3[mt][nt][r];
                float hv = 0.f;
                if (valid) {
                    float tw = (e < NROUT) ? tokw[e * TTOK + slot] : 1.0f;
                    hv = h1 / (1.f + __expf(-h1)) * h3 * tw;
                }
                if (e < NROUT)
                    Hc[((size_t)e * TTOK + slot) * INTERSZ + n0 + n] = f2bf(hv);
                else
                    Hs[(size_t)slot * DIMSZ + (e - NROUT) * INTERSZ + n0 + n] = f2bf(hv);
            }
        }
    }
}

// ---- GEMM2 unified: BM=64 BN=128; out zero-initialized, ALL blocks atomicAdd ----
// z<16 routed (K=512, gathered token scatter), z==16 shared (K=1024, identity rows)
__global__ __launch_bounds__(256) void gemm2u(
    const u16* __restrict__ Hc, const u16* __restrict__ Hs,
    const u16* __restrict__ W2b, const u16* __restrict__ W2sb,
    const int* __restrict__ counts, const int* __restrict__ tokidx,
    float* __restrict__ out) {
    const int e = blockIdx.z;
    const bool routed = (e < NROUT);
    const int cnt = routed ? counts[e] : TTOK;
    const int m0 = blockIdx.y * 64;
    if (m0 >= cnt) return;
    const int n0 = blockIdx.x * 128;
    const int klen = routed ? INTERSZ : DIMSZ;
    __shared__ u16 As[64 * 64], Bs[128 * 64];
    const u16* A0 = routed ? Hc + ((size_t)e * TTOK + m0) * INTERSZ
                           : Hs + (size_t)m0 * DIMSZ;
    const u16* B0 = routed ? W2b + ((size_t)e * DIMSZ + n0) * INTERSZ
                           : W2sb + (size_t)n0 * DIMSZ;
    const int tid = threadIdx.x;
    const int wave = tid >> 6, lane = tid & 63;
    const int wm = (wave >> 1) * 32, wn = (wave & 1) * 64;
    const int lr = lane & 15, lq = lane >> 4;

    int rowa[2], cgsa[2];
    #pragma unroll
    for (int i = 0; i < 2; ++i) {
        int c = tid + i * 256;
        rowa[i] = c >> 3;
        cgsa[i] = ((c & 7) ^ (rowa[i] & 7)) * 8;
    }
    int rowb[4], cgsb[4];
    #pragma unroll
    for (int i = 0; i < 4; ++i) {
        int c = tid + i * 256;
        rowb[i] = c >> 3;
        cgsb[i] = ((c & 7) ^ (rowb[i] & 7)) * 8;
    }

    f32x4 acc[2][4] = {};
    for (int kt = 0; kt < klen / 64; ++kt) {
        const int k0 = kt * 64;
        #pragma unroll
        for (int i = 0; i < 2; ++i) {
            int c = tid + i * 256;
            gl2lds16(A0 + (size_t)rowa[i] * klen + k0 + cgsa[i], &As[c * 8]);
        }
        #pragma unroll
        for (int i = 0; i < 4; ++i) {
            int c = tid + i * 256;
            gl2lds16(B0 + (size_t)rowb[i] * klen + k0 + cgsb[i], &Bs[c * 8]);
        }
        __syncthreads();
        #pragma unroll
        for (int ks = 0; ks < 2; ++ks) {
            bf16x8 af[2], bfr[4];
            const int g = lq + ks * 4;
            #pragma unroll
            for (int mt = 0; mt < 2; ++mt) {
                int m = wm + mt * 16 + lr;
                af[mt] = *(const bf16x8*)&As[(m * 8 + (g ^ (m & 7))) * 8];
            }
            #pragma unroll
            for (int nt = 0; nt < 4; ++nt) {
                int n = wn + nt * 16 + lr;
                bfr[nt] = *(const bf16x8*)&Bs[(n * 8 + (g ^ (n & 7))) * 8];
            }
            #pragma unroll
            for (int mt = 0; mt < 2; ++mt) {
                #pragma unroll
                for (int nt = 0; nt < 4; ++nt) {
                    acc[mt][nt] = __builtin_amdgcn_mfma_f32_16x16x32_bf16(af[mt], bfr[nt], acc[mt][nt], 0, 0, 0);
                }
            }
        }
        __syncthreads();
    }
    #pragma unroll
    for (int mt = 0; mt < 2; ++mt) {
        #pragma unroll
        for (int r = 0; r < 4; ++r) {
            int m = wm + mt * 16 + lq * 4 + r;
            int slot = m0 + m;
            if (slot < cnt) {
                int t = routed ? tokidx[e * TTOK + slot] : slot;
                #pragma unroll
                for (int nt = 0; nt < 4; ++nt) {
                    int n = wn + nt * 16 + lr;
                    unsafeAtomicAdd(&out[(size_t)t * DIMSZ + n0 + n], acc[mt][nt][r]);
                }
            }
        }
    }
}

extern "C" void kernel_launch(void* const* d_in, const int* in_sizes, int n_in,
                              void* d_out, int out_size, void* d_ws, size_t ws_size,
                              hipStream_t stream) {
    const float* x      = (const float*)d_in[0];
    const float* gate_w = (const float*)d_in[1];
    const float* w1     = (const float*)d_in[2];
    const float* w2     = (const float*)d_in[3];
    const float* w3     = (const float*)d_in[4];
    const float* sw1    = (const float*)d_in[5];
    const float* sw2    = (const float*)d_in[6];
    const float* sw3    = (const float*)d_in[7];
    float* out = (float*)d_out;

    char* ws = (char*)d_ws;
    const size_t SZ_W   = (size_t)(NROUT + 2) * INTERSZ * DIMSZ * 2;
    const size_t SZ_XBF = (size_t)TTOK * DIMSZ * 2;
    u16*   W1b    = (u16*)(ws);
    u16*   W3b    = (u16*)(ws + SZ_W);
    u16*   W2all  = (u16*)(ws + 2 * SZ_W);
    u16*   Xbf    = (u16*)(ws + 3 * SZ_W);
    char*  route  = ws + 3 * SZ_W + SZ_XBF;
    int*   counts = (int*)route;
    int*   topi   = (int*)(route + 256);
    float2* topw  = (float2*)(route + 256 + TTOK * 4);
    int*   tokidx = (int*)(route + 256 + TTOK * 12);
    float* tokw   = (float*)(route + 256 + TTOK * 12 + 16 * TTOK * 4);
    char*  hbuf   = route + 256 + TTOK * 12 + 2 * (size_t)16 * TTOK * 4;
    u16*   Hc     = (u16*)hbuf;                                        // [16][2048][512]
    u16*   Hs     = (u16*)(hbuf + (size_t)NROUT * TTOK * INTERSZ * 2); // [2048][1024]
    u16*   W2sb   = W2all + (size_t)NROUT * DIMSZ * INTERSZ;

    prep<<<dim3(2048, 4), 256, 0, stream>>>(
        w1, sw1, w3, sw3, w2, sw2, W1b, W3b, W2all,
        x, gate_w, topi, topw, Xbf, out);
    route_kernel<<<NROUT, 256, 0, stream>>>(topi, topw, counts, tokidx, tokw);
    gemm1s<<<dim3(INTERSZ / 128, TTOK / 64, NROUT + 2), 256, 0, stream>>>(
        Xbf, W1b, W3b, counts, tokidx, tokw, Hc, Hs);
    gemm2u<<<dim3(DIMSZ / 128, TTOK / 64, NROUT + 1), 256, 0, stream>>>(
        Hc, Hs, W2all, W2sb, counts, tokidx, out);
}